// Round 1
// baseline (582.977 us; speedup 1.0000x reference)
//
#include <hip/hip_runtime.h>
#include <stdint.h>

#define IN_C 128
#define OUT_C 64
#define NEG_SLOPE 0.2f

// ---------------- helpers ----------------
__device__ __forceinline__ unsigned int fenc(float f) {
  unsigned int u = __float_as_uint(f);
  return (u & 0x80000000u) ? ~u : (u | 0x80000000u);
}
__device__ __forceinline__ float fdec(unsigned int u) {
  unsigned int b = (u & 0x80000000u) ? (u & 0x7fffffffu) : ~u;
  return __uint_as_float(b);
}
__device__ __forceinline__ unsigned long long key64(float v, int i) {
  unsigned int fk = fenc(v);
  return (((unsigned long long)fk) << 32) | (unsigned long long)(0xffffffffu - (unsigned int)i);
}

// ---------------- init: zero scratch + set select state ----------------
__global__ __launch_bounds__(256) void k_init(unsigned int* z, int nz,
                                              unsigned int* sel, unsigned int k) {
  int i = blockIdx.x * 256 + threadIdx.x;
  if (i < nz) z[i] = 0u;
  if (i == 0) { sel[0] = 0u; sel[1] = 0u; sel[2] = k; sel[3] = 0u; }
}

// ---------------- h = x @ W  (fp32, LDS-tiled, 64 rows/block) ----------------
__global__ __launch_bounds__(256) void k_gemm(const float* __restrict__ x,
                                              const float* __restrict__ w,
                                              float* __restrict__ h, int N) {
  __shared__ float sw[IN_C * OUT_C];   // 32 KB, sw[k*64+c]
  __shared__ float sx[64 * 65];        // 16.25 KB, sx[kl*65 + r]  (padded, transposed)
  int tid = threadIdx.x;
  int rbase = blockIdx.x * 64;

  for (int i = tid; i < (IN_C * OUT_C) / 4; i += 256)
    ((float4*)sw)[i] = ((const float4*)w)[i];

  int c0 = (tid & 7) * 8;
  int r0 = (tid >> 3) * 2;
  float acc[2][8];
#pragma unroll
  for (int i = 0; i < 2; i++)
#pragma unroll
    for (int j = 0; j < 8; j++) acc[i][j] = 0.f;

  for (int half = 0; half < 2; ++half) {
    __syncthreads();
    for (int i = tid; i < 4096; i += 256) {
      int kl = i & 63, r = i >> 6;
      int row = rbase + r;
      float v = 0.f;
      if (row < N) v = x[(size_t)row * IN_C + half * 64 + kl];
      sx[kl * 65 + r] = v;   // lanes: consecutive kl -> banks (kl+r)%32, conflict-free
    }
    __syncthreads();
#pragma unroll 2
    for (int kl = 0; kl < 64; ++kl) {
      float xr0 = sx[kl * 65 + r0];
      float xr1 = sx[kl * 65 + r0 + 1];
      const float* wp = &sw[(half * 64 + kl) * OUT_C + c0];
      float wv[8];
#pragma unroll
      for (int j = 0; j < 8; ++j) wv[j] = wp[j];
#pragma unroll
      for (int j = 0; j < 8; ++j) {
        acc[0][j] += xr0 * wv[j];
        acc[1][j] += xr1 * wv[j];
      }
    }
  }
#pragma unroll
  for (int i = 0; i < 2; i++) {
    int row = rbase + r0 + i;
    if (row < N) {
      float4 o0 = make_float4(acc[i][0], acc[i][1], acc[i][2], acc[i][3]);
      float4 o1 = make_float4(acc[i][4], acc[i][5], acc[i][6], acc[i][7]);
      *(float4*)&h[(size_t)row * OUT_C + c0] = o0;
      *(float4*)&h[(size_t)row * OUT_C + c0 + 4] = o1;
    }
  }
}

// ---------------- per-node attention partials: ai = h.att[:64], aj = h.att[64:] ----------------
__global__ __launch_bounds__(256) void k_aiaj(const float* __restrict__ h,
                                              const float* __restrict__ att,
                                              float* __restrict__ ai, float* __restrict__ aj, int N) {
  int node = blockIdx.x * 4 + (threadIdx.x >> 6);
  int lane = threadIdx.x & 63;
  if (node >= N) return;
  float hv = h[(size_t)node * OUT_C + lane];
  float pi = hv * att[lane];
  float pj = hv * att[OUT_C + lane];
#pragma unroll
  for (int o = 32; o > 0; o >>= 1) {
    pi += __shfl_xor(pi, o);
    pj += __shfl_xor(pj, o);
  }
  if (lane == 0) { ai[node] = pi; aj[node] = pj; }
}

// ---------------- raw alpha + segment max by target ----------------
__global__ __launch_bounds__(256) void k_alpha_max(const int* __restrict__ src, const int* __restrict__ tgt,
                                                   const float* __restrict__ ai, const float* __restrict__ aj,
                                                   float* __restrict__ alpha, unsigned int* __restrict__ menc,
                                                   int E, int EN) {
  int e = blockIdx.x * 256 + threadIdx.x;
  if (e >= EN) return;
  int s, t;
  if (e < E) { s = src[e]; t = tgt[e]; } else { s = t = e - E; }
  float a = ai[t] + aj[s];
  a = a > 0.f ? a : NEG_SLOPE * a;
  alpha[e] = a;
  atomicMax(&menc[t], fenc(a));
}

// ---------------- exp(alpha - max) + segment denom ----------------
__global__ __launch_bounds__(256) void k_exp_denom(const int* __restrict__ tgt,
                                                   float* __restrict__ alpha,
                                                   const unsigned int* __restrict__ menc,
                                                   float* __restrict__ denom, int E, int EN) {
  int e = blockIdx.x * 256 + threadIdx.x;
  if (e >= EN) return;
  int t = (e < E) ? tgt[e] : e - E;
  float a = expf(alpha[e] - fdec(menc[t]));
  alpha[e] = a;
  atomicAdd(&denom[t], a);
}

// ---------------- normalize + per-source alpha_sum ----------------
__global__ __launch_bounds__(256) void k_norm_asum(const int* __restrict__ src, const int* __restrict__ tgt,
                                                   float* __restrict__ alpha,
                                                   const float* __restrict__ denom,
                                                   float* __restrict__ asum, int E, int EN) {
  int e = blockIdx.x * 256 + threadIdx.x;
  if (e >= EN) return;
  int s, t;
  if (e < E) { s = src[e]; t = tgt[e]; } else { s = t = e - E; }
  float a = alpha[e] / (denom[t] + 1e-16f);
  alpha[e] = a;
  atomicAdd(&asum[s], a);
}

// ---------------- radix-select (8 passes, MSB-first, 8-bit digits) ----------------
__global__ __launch_bounds__(256) void k_hist(const float* __restrict__ asum,
                                              unsigned int* __restrict__ hist8,
                                              const unsigned int* __restrict__ sel,
                                              int N, int pass) {
  __shared__ unsigned int lh[256];
  lh[threadIdx.x] = 0u;
  __syncthreads();
  unsigned long long prefix = ((const unsigned long long*)sel)[0];
  int shift = 56 - 8 * pass;
  int i = blockIdx.x * 256 + threadIdx.x;
  if (i < N) {
    unsigned long long k = key64(asum[i], i);
    bool ok = (pass == 0) || ((k >> (shift + 8)) == prefix);
    if (ok) atomicAdd(&lh[(unsigned int)(k >> shift) & 255u], 1u);
  }
  __syncthreads();
  if (lh[threadIdx.x]) atomicAdd(&hist8[pass * 256 + threadIdx.x], lh[threadIdx.x]);
}

__global__ __launch_bounds__(256) void k_pick(const unsigned int* __restrict__ hist8,
                                              unsigned int* __restrict__ sel, int pass) {
  __shared__ unsigned int s[256];
  int tid = threadIdx.x;
  unsigned int krem = sel[2];            // read BEFORE any writer can update
  unsigned int hv = hist8[pass * 256 + (255 - tid)];
  s[tid] = hv;
  __syncthreads();
  for (int o = 1; o < 256; o <<= 1) {
    unsigned int t = (tid >= o) ? s[tid - o] : 0u;
    __syncthreads();
    s[tid] += t;
    __syncthreads();
  }
  unsigned int cum = s[tid];
  unsigned int prev = (tid > 0) ? s[tid - 1] : 0u;
  if (cum >= krem && prev < krem) {      // exactly one thread
    int d = 255 - tid;
    unsigned long long prefix = ((unsigned long long*)sel)[0];
    ((unsigned long long*)sel)[0] = (prefix << 8) | (unsigned long long)(unsigned int)d;
    sel[2] = krem - prev;
  }
}

// ---------------- node mask from threshold key ----------------
__global__ __launch_bounds__(256) void k_node_mask(const float* __restrict__ asum,
                                                   const unsigned int* __restrict__ sel,
                                                   unsigned int* __restrict__ nm,
                                                   float* __restrict__ out_node, int N) {
  int i = blockIdx.x * 256 + threadIdx.x;
  if (i >= N) return;
  unsigned long long T = ((const unsigned long long*)sel)[0];
  bool m = key64(asum[i], i) >= T;
  nm[i] = m ? 1u : 0u;
  out_node[i] = m ? 1.f : 0.f;
}

// ---------------- edge mask output + surviving-edge degree count ----------------
__global__ __launch_bounds__(256) void k_edge_mask_deg(const int* __restrict__ src, const int* __restrict__ tgt,
                                                       const unsigned int* __restrict__ nm,
                                                       float* __restrict__ out_edge,
                                                       unsigned int* __restrict__ deg, int E, int EN) {
  int e = blockIdx.x * 256 + threadIdx.x;
  if (e >= EN) return;
  int s, t;
  if (e < E) { s = src[e]; t = tgt[e]; } else { s = t = e - E; }
  bool m = nm[s] && nm[t];
  out_edge[e] = m ? 1.f : 0.f;
  if (m) atomicAdd(&deg[t], 1u);
}

// ---------------- 3-kernel exclusive scan over deg[N+1] ----------------
__global__ __launch_bounds__(256) void k_scanA(const unsigned int* __restrict__ deg,
                                               unsigned int* __restrict__ off,
                                               unsigned int* __restrict__ bsum, int n) {
  __shared__ unsigned int s[256];
  int i = blockIdx.x * 256 + threadIdx.x;
  unsigned int v = (i < n) ? deg[i] : 0u;
  s[threadIdx.x] = v;
  __syncthreads();
  for (int o = 1; o < 256; o <<= 1) {
    unsigned int t = (threadIdx.x >= (unsigned)o) ? s[threadIdx.x - o] : 0u;
    __syncthreads();
    s[threadIdx.x] += t;
    __syncthreads();
  }
  if (i < n) off[i] = s[threadIdx.x] - v;             // exclusive within block
  if (threadIdx.x == 255) bsum[blockIdx.x] = s[255];  // block total
}

__global__ __launch_bounds__(512) void k_scanB(unsigned int* __restrict__ bsum, int nb) {
  __shared__ unsigned int s[512];
  int tid = threadIdx.x;
  unsigned int v = (tid < nb) ? bsum[tid] : 0u;
  s[tid] = v;
  __syncthreads();
  for (int o = 1; o < 512; o <<= 1) {
    unsigned int t = (tid >= o) ? s[tid - o] : 0u;
    __syncthreads();
    s[tid] += t;
    __syncthreads();
  }
  if (tid < nb) bsum[tid] = s[tid] - v;               // exclusive block offsets
}

__global__ __launch_bounds__(256) void k_scanC(unsigned int* __restrict__ off,
                                               const unsigned int* __restrict__ bsum,
                                               unsigned int* __restrict__ cur, int n) {
  int i = blockIdx.x * 256 + threadIdx.x;
  if (i >= n) return;
  unsigned int o = off[i] + bsum[blockIdx.x];
  off[i] = o;
  cur[i] = o;
}

// ---------------- scatter surviving edges into CSR-by-target ----------------
__global__ __launch_bounds__(256) void k_scatter(const int* __restrict__ src, const int* __restrict__ tgt,
                                                 const unsigned int* __restrict__ nm,
                                                 const float* __restrict__ alpha,
                                                 unsigned int* __restrict__ cur,
                                                 unsigned int* __restrict__ csr_src,
                                                 float* __restrict__ csr_alpha, int E, int EN) {
  int e = blockIdx.x * 256 + threadIdx.x;
  if (e >= EN) return;
  int s, t;
  if (e < E) { s = src[e]; t = tgt[e]; } else { s = t = e - E; }
  if (nm[s] && nm[t]) {
    unsigned int p = atomicAdd(&cur[t], 1u);
    csr_src[p] = (unsigned int)s;
    csr_alpha[p] = alpha[e];
  }
}

// ---------------- gather-aggregate: one wave per node, lane = channel ----------------
__global__ __launch_bounds__(256) void k_aggregate(const unsigned int* __restrict__ off,
                                                   const unsigned int* __restrict__ csr_src,
                                                   const float* __restrict__ csr_alpha,
                                                   const float* __restrict__ h,
                                                   float* __restrict__ out, int N) {
  int node = blockIdx.x * 4 + (threadIdx.x >> 6);
  int lane = threadIdx.x & 63;
  if (node >= N) return;
  unsigned int b = off[node], en = off[node + 1];
  float acc = 0.f;
  for (unsigned int e = b; e < en; ++e) {
    unsigned int s = csr_src[e];
    float a = csr_alpha[e];
    acc += a * h[(size_t)s * OUT_C + lane];
  }
  out[(size_t)node * OUT_C + lane] = acc;
}

// ---------------- launch ----------------
extern "C" void kernel_launch(void* const* d_in, const int* in_sizes, int n_in,
                              void* d_out, int out_size, void* d_ws, size_t ws_size,
                              hipStream_t stream) {
  const float* x   = (const float*)d_in[0];
  const float* w   = (const float*)d_in[1];
  const float* att = (const float*)d_in[2];
  const int*   ei  = (const int*)d_in[3];

  int N = in_sizes[0] / IN_C;
  int E = in_sizes[3] / 2;
  int EN = E + N;
  const int* src = ei;
  const int* tgt = ei + E;

  float* out      = (float*)d_out;
  float* out_edge = out + (size_t)N * OUT_C;
  float* out_node = out_edge + (size_t)EN;

  // workspace carve-out (256B aligned each)
  char* p = (char*)d_ws;
  auto alloc = [&](size_t bytes) -> char* {
    char* r = p;
    p += (bytes + 255) & ~(size_t)255;
    return r;
  };
  float* h     = (float*)alloc((size_t)N * OUT_C * 4);
  float* ai    = (float*)alloc((size_t)N * 4);
  float* aj    = (float*)alloc((size_t)N * 4);
  float* alpha = (float*)alloc((size_t)EN * 4);
  char* zstart = p;                                   // ---- zeroed region begins
  unsigned int* menc  = (unsigned int*)alloc((size_t)N * 4);
  float*        denom = (float*)alloc((size_t)N * 4);
  float*        asum  = (float*)alloc((size_t)N * 4);
  unsigned int* deg   = (unsigned int*)alloc((size_t)(N + 1) * 4);
  unsigned int* hist8 = (unsigned int*)alloc(2048 * 4);
  int nz = (int)((p - zstart) / 4);                   // ---- zeroed region ends
  unsigned int* sel   = (unsigned int*)alloc(256);
  unsigned int* off   = (unsigned int*)alloc((size_t)(N + 1) * 4);
  unsigned int* cur   = (unsigned int*)alloc((size_t)(N + 1) * 4);
  unsigned int* bsum  = (unsigned int*)alloc(512 * 4);
  unsigned int* csr_src   = (unsigned int*)alloc((size_t)EN * 4);
  float*        csr_alpha = (float*)alloc((size_t)EN * 4);

  unsigned int kSel = (unsigned int)((N + 1) / 2);    // ceil(0.5*N)

  int gInit = (nz + 255) / 256;
  int gRow  = (N + 63) / 64;
  int gNode4 = (N + 3) / 4;
  int gN    = (N + 255) / 256;
  int gE    = (EN + 255) / 256;
  int nScan = ((N + 1) + 255) / 256;

  k_init<<<gInit, 256, 0, stream>>>((unsigned int*)zstart, nz, sel, kSel);
  k_gemm<<<gRow, 256, 0, stream>>>(x, w, h, N);
  k_aiaj<<<gNode4, 256, 0, stream>>>(h, att, ai, aj, N);
  k_alpha_max<<<gE, 256, 0, stream>>>(src, tgt, ai, aj, alpha, menc, E, EN);
  k_exp_denom<<<gE, 256, 0, stream>>>(tgt, alpha, menc, denom, E, EN);
  k_norm_asum<<<gE, 256, 0, stream>>>(src, tgt, alpha, denom, asum, E, EN);
  for (int pass = 0; pass < 8; ++pass) {
    k_hist<<<gN, 256, 0, stream>>>(asum, hist8, sel, N, pass);
    k_pick<<<1, 256, 0, stream>>>(hist8, sel, pass);
  }
  k_node_mask<<<gN, 256, 0, stream>>>(asum, sel, (unsigned int*)off /*reuse? no*/, out_node, N);
  // NOTE: nm stored in `cur`? keep dedicated: reuse `off` is wrong — use deg? deg still needed.
  // Use a dedicated array: reuse bsum? too small. -> use menc (no longer needed after k_exp_denom... but cheap to keep separate):
  // (correctness over cleverness: menc is free after k_exp_denom, reuse it as node-mask storage)
  // Re-launch with menc as nm:
  k_node_mask<<<gN, 256, 0, stream>>>(asum, sel, menc, out_node, N);
  k_edge_mask_deg<<<gE, 256, 0, stream>>>(src, tgt, menc, out_edge, deg, E, EN);
  k_scanA<<<nScan, 256, 0, stream>>>(deg, off, bsum, N + 1);
  k_scanB<<<1, 512, 0, stream>>>(bsum, nScan);
  k_scanC<<<nScan, 256, 0, stream>>>(off, bsum, cur, N + 1);
  k_scatter<<<gE, 256, 0, stream>>>(src, tgt, menc, alpha, cur, csr_src, csr_alpha, E, EN);
  k_aggregate<<<gNode4, 256, 0, stream>>>(off, csr_src, csr_alpha, h, out, N);
}

// Round 2
// 523.388 us; speedup vs baseline: 1.1139x; 1.1139x over previous
//
#include <hip/hip_runtime.h>
#include <stdint.h>

#define IN_C 128
#define OUT_C 64
#define NEG_SLOPE 0.2f
#define RB 256      // blocks in coarse-partition kernels
#define RBINS 512   // coarse bins (node>>8, node<131072)
#define STAGE 8192  // per-bucket LDS staging capacity (avg bucket ~4350)

typedef unsigned int u32;
typedef unsigned long long u64;

// ---------------- helpers ----------------
__device__ __forceinline__ u32 fenc(float f) {
  u32 u = __float_as_uint(f);
  return (u & 0x80000000u) ? ~u : (u | 0x80000000u);
}
__device__ __forceinline__ u64 key64(float v, int i) {
  return (((u64)fenc(v)) << 32) | (u64)(0xffffffffu - (u32)i);
}
__device__ __forceinline__ void edge_st(const int* src, const int* tgt, int E, int e,
                                        int& s, int& t) {
  if (e < E) { s = src[e]; t = tgt[e]; } else { s = t = e - E; }
}

// ---------------- init: zero select state ----------------
__global__ __launch_bounds__(256) void k_init(u32* hist8, u32* done, u32* sel, u32 k) {
  int i = blockIdx.x * 256 + threadIdx.x;
  if (i < 2048) hist8[i] = 0u;
  if (i < 8) done[i] = 0u;
  if (i == 0) { sel[0] = 0u; sel[1] = 0u; sel[2] = k; sel[3] = 0u; }
}

// ---------------- h = x @ W + fused ai/aj epilogue ----------------
__global__ __launch_bounds__(256) void k_gemm(const float* __restrict__ x,
                                              const float* __restrict__ w,
                                              const float* __restrict__ att,
                                              float* __restrict__ h,
                                              float* __restrict__ ai, float* __restrict__ aj,
                                              int N) {
  __shared__ float sw[IN_C * OUT_C];
  __shared__ float sx[64 * 65];
  int tid = threadIdx.x;
  int rbase = blockIdx.x * 64;

  for (int i = tid; i < (IN_C * OUT_C) / 4; i += 256)
    ((float4*)sw)[i] = ((const float4*)w)[i];

  int c0 = (tid & 7) * 8;
  int r0 = (tid >> 3) * 2;
  float acc[2][8];
#pragma unroll
  for (int i = 0; i < 2; i++)
#pragma unroll
    for (int j = 0; j < 8; j++) acc[i][j] = 0.f;

  for (int half = 0; half < 2; ++half) {
    __syncthreads();
    for (int i = tid; i < 4096; i += 256) {
      int kl = i & 63, r = i >> 6;
      int row = rbase + r;
      float v = 0.f;
      if (row < N) v = x[(size_t)row * IN_C + half * 64 + kl];
      sx[kl * 65 + r] = v;
    }
    __syncthreads();
#pragma unroll 2
    for (int kl = 0; kl < 64; ++kl) {
      float xr0 = sx[kl * 65 + r0];
      float xr1 = sx[kl * 65 + r0 + 1];
      const float* wp = &sw[(half * 64 + kl) * OUT_C + c0];
      float wv[8];
#pragma unroll
      for (int j = 0; j < 8; ++j) wv[j] = wp[j];
#pragma unroll
      for (int j = 0; j < 8; ++j) {
        acc[0][j] += xr0 * wv[j];
        acc[1][j] += xr1 * wv[j];
      }
    }
  }
  float pi0 = 0.f, pj0 = 0.f, pi1 = 0.f, pj1 = 0.f;
#pragma unroll
  for (int j = 0; j < 8; ++j) {
    float a0 = att[c0 + j], a1 = att[OUT_C + c0 + j];
    pi0 += acc[0][j] * a0; pj0 += acc[0][j] * a1;
    pi1 += acc[1][j] * a0; pj1 += acc[1][j] * a1;
  }
#pragma unroll
  for (int o = 1; o < 8; o <<= 1) {
    pi0 += __shfl_xor(pi0, o); pj0 += __shfl_xor(pj0, o);
    pi1 += __shfl_xor(pi1, o); pj1 += __shfl_xor(pj1, o);
  }
#pragma unroll
  for (int i = 0; i < 2; i++) {
    int row = rbase + r0 + i;
    if (row < N) {
      *(float4*)&h[(size_t)row * OUT_C + c0]     = make_float4(acc[i][0], acc[i][1], acc[i][2], acc[i][3]);
      *(float4*)&h[(size_t)row * OUT_C + c0 + 4] = make_float4(acc[i][4], acc[i][5], acc[i][6], acc[i][7]);
    }
  }
  if ((tid & 7) == 0) {
    int row = rbase + r0;
    if (row < N)     { ai[row] = pi0; aj[row] = pj0; }
    if (row + 1 < N) { ai[row + 1] = pi1; aj[row + 1] = pj1; }
  }
}

// ---------------- coarse hist by tgt>>8 (pass over edges incl self loops) ----------------
__global__ __launch_bounds__(256) void k_rhist_t(const int* __restrict__ src, const int* __restrict__ tgt,
                                                 int E, int EN, int chunk, u32* __restrict__ gh) {
  __shared__ u32 lh[RBINS];
  int tid = threadIdx.x, b = blockIdx.x;
  for (int d = tid; d < RBINS; d += 256) lh[d] = 0u;
  __syncthreads();
  int lo = b * chunk, hi = min(lo + chunk, EN);
  for (int e = lo + tid; e < hi; e += 256) {
    int s, t; edge_st(src, tgt, E, e, s, t);
    atomicAdd(&lh[((u32)t) >> 8], 1u);
  }
  __syncthreads();
  for (int d = tid; d < RBINS; d += 256) gh[d * RB + b] = lh[d];
}

// ---------------- generic 3-kernel exclusive scan (n <= 131072) ----------------
__global__ __launch_bounds__(256) void k_scanA(const u32* __restrict__ in, u32* __restrict__ out,
                                               u32* __restrict__ bsum, int n) {
  __shared__ u32 s[256];
  int i = blockIdx.x * 256 + threadIdx.x;
  u32 v = (i < n) ? in[i] : 0u;
  s[threadIdx.x] = v;
  __syncthreads();
  for (int o = 1; o < 256; o <<= 1) {
    u32 t = (threadIdx.x >= (unsigned)o) ? s[threadIdx.x - o] : 0u;
    __syncthreads();
    s[threadIdx.x] += t;
    __syncthreads();
  }
  if (i < n) out[i] = s[threadIdx.x] - v;
  if (threadIdx.x == 255) bsum[blockIdx.x] = s[255];
}

__global__ __launch_bounds__(512) void k_scanB(u32* __restrict__ bsum, int nb) {
  __shared__ u32 s[512];
  int tid = threadIdx.x;
  u32 v = (tid < nb) ? bsum[tid] : 0u;
  s[tid] = v;
  __syncthreads();
  for (int o = 1; o < 512; o <<= 1) {
    u32 t = (tid >= o) ? s[tid - o] : 0u;
    __syncthreads();
    s[tid] += t;
    __syncthreads();
  }
  if (tid < nb) bsum[tid] = s[tid] - v;
}

__global__ __launch_bounds__(256) void k_scanC(u32* __restrict__ out, const u32* __restrict__ bsum, int n) {
  int i = blockIdx.x * 256 + threadIdx.x;
  if (i < n) out[i] += bsum[blockIdx.x];
}

// ---------------- coarse scatter by tgt>>8: edges -> bufB items (tgt<<32|src) ----------------
__global__ __launch_bounds__(256) void k_rscatter_t(const int* __restrict__ src, const int* __restrict__ tgt,
                                                    int E, int EN, int chunk,
                                                    const u32* __restrict__ gh, u64* __restrict__ bufB) {
  __shared__ u32 cnt[RBINS];
  int tid = threadIdx.x, b = blockIdx.x;
  for (int d = tid; d < RBINS; d += 256) cnt[d] = gh[d * RB + b];
  __syncthreads();
  int lo = b * chunk, hi = min(lo + chunk, EN);
  for (int e = lo + tid; e < hi; e += 256) {
    int s, t; edge_st(src, tgt, E, e, s, t);
    u32 p = atomicAdd(&cnt[((u32)t) >> 8], 1u);
    bufB[p] = (((u64)(u32)t) << 32) | (u32)s;
  }
}

// ---------------- fine partition within coarse bucket (by key>>32 & 255) ----------------
__global__ __launch_bounds__(256) void k_rpass2(const u64* __restrict__ in, u64* __restrict__ out,
                                                const u32* __restrict__ gh, int EN) {
  __shared__ u32 hist[256];
  __shared__ u32 sc[256];
  __shared__ u64 stage[STAGE];
  int tid = threadIdx.x, d = blockIdx.x;
  u32 start = gh[d * RB];
  u32 end = (d < RBINS - 1) ? gh[(d + 1) * RB] : (u32)EN;
  int sz = (int)(end - start);
  hist[tid] = 0u;
  __syncthreads();
  for (u32 p = start + tid; p < end; p += 256)
    atomicAdd(&hist[(u32)(in[p] >> 32) & 255u], 1u);
  __syncthreads();
  u32 hv = hist[tid];
  sc[tid] = hv;
  __syncthreads();
  for (int o = 1; o < 256; o <<= 1) {
    u32 t = (tid >= o) ? sc[tid - o] : 0u;
    __syncthreads();
    sc[tid] += t;
    __syncthreads();
  }
  hist[tid] = sc[tid] - hv;   // exclusive base -> running counter
  __syncthreads();
  bool staged = (sz <= STAGE);
  for (u32 p = start + tid; p < end; p += 256) {
    u64 it = in[p];
    u32 fd = (u32)(it >> 32) & 255u;
    u32 lp = atomicAdd(&hist[fd], 1u);
    if (staged) stage[lp] = it;
    else out[start + lp] = it;
  }
  __syncthreads();
  if (staged)
    for (int i = tid; i < sz; i += 256) out[start + i] = stage[i];
}

// ---------------- CSR offsets from grouped keys ----------------
__global__ __launch_bounds__(256) void k_runs(const u64* __restrict__ csr, u32* __restrict__ off,
                                              int N, int EN) {
  int p = blockIdx.x * 256 + threadIdx.x;
  if (p >= EN) return;
  u32 t = (u32)(csr[p] >> 32);
  u32 tp = (p > 0) ? (u32)(csr[p - 1] >> 32) : 0xffffffffu;
  if (p == 0 || t != tp) off[t] = (u32)p;
  if (p == 0) off[N] = (u32)EN;
}

// ---------------- per-node softmax (wave per node, zero atomics) ----------------
__global__ __launch_bounds__(256) void k_softmax(const u64* __restrict__ csr, const u32* __restrict__ off,
                                                 const float* __restrict__ ai, const float* __restrict__ aj,
                                                 float* __restrict__ alpha, int N) {
  int node = blockIdx.x * 4 + (threadIdx.x >> 6);
  int lane = threadIdx.x & 63;
  if (node >= N) return;
  u32 b = off[node], e2 = off[node + 1];
  float an = ai[node];
  float mx = -1e30f;
  for (u32 p = b + lane; p < e2; p += 64) {
    u32 s = (u32)csr[p];
    float a = an + aj[s];
    a = a > 0.f ? a : NEG_SLOPE * a;
    alpha[p] = a;
    mx = fmaxf(mx, a);
  }
#pragma unroll
  for (int o = 32; o > 0; o >>= 1) mx = fmaxf(mx, __shfl_xor(mx, o));
  float sm = 0.f;
  for (u32 p = b + lane; p < e2; p += 64) {
    float v = expf(alpha[p] - mx);
    alpha[p] = v;
    sm += v;
  }
#pragma unroll
  for (int o = 32; o > 0; o >>= 1) sm += __shfl_xor(sm, o);
  float inv = 1.f / (sm + 1e-16f);
  for (u32 p = b + lane; p < e2; p += 64) alpha[p] *= inv;
}

// ---------------- coarse hist by src>>8 over CSR entries ----------------
__global__ __launch_bounds__(256) void k_rhist_s(const u64* __restrict__ csr, int EN, int chunk,
                                                 u32* __restrict__ gh) {
  __shared__ u32 lh[RBINS];
  int tid = threadIdx.x, b = blockIdx.x;
  for (int d = tid; d < RBINS; d += 256) lh[d] = 0u;
  __syncthreads();
  int lo = b * chunk, hi = min(lo + chunk, EN);
  for (int e = lo + tid; e < hi; e += 256)
    atomicAdd(&lh[((u32)csr[e]) >> 8], 1u);
  __syncthreads();
  for (int d = tid; d < RBINS; d += 256) gh[d * RB + b] = lh[d];
}

// ---------------- coarse scatter by src>>8: (src<<32 | alpha_bits) ----------------
__global__ __launch_bounds__(256) void k_rscatter_s(const u64* __restrict__ csr,
                                                    const float* __restrict__ alpha,
                                                    int EN, int chunk,
                                                    const u32* __restrict__ gh, u64* __restrict__ bufB) {
  __shared__ u32 cnt[RBINS];
  int tid = threadIdx.x, b = blockIdx.x;
  for (int d = tid; d < RBINS; d += 256) cnt[d] = gh[d * RB + b];
  __syncthreads();
  int lo = b * chunk, hi = min(lo + chunk, EN);
  for (int e = lo + tid; e < hi; e += 256) {
    u32 s = (u32)csr[e];
    u32 p = atomicAdd(&cnt[s >> 8], 1u);
    bufB[p] = (((u64)s) << 32) | __float_as_uint(alpha[e]);
  }
}

// ---------------- per-bucket alpha_sum accumulation (LDS fp bins) ----------------
__global__ __launch_bounds__(256) void k_asum_acc(const u64* __restrict__ bufB,
                                                  const u32* __restrict__ gh,
                                                  float* __restrict__ asum, int N, int EN) {
  __shared__ float sums[256];
  int tid = threadIdx.x, d = blockIdx.x;
  u32 start = gh[d * RB];
  u32 end = (d < RBINS - 1) ? gh[(d + 1) * RB] : (u32)EN;
  sums[tid] = 0.f;
  __syncthreads();
  for (u32 p = start + tid; p < end; p += 256) {
    u64 it = bufB[p];
    atomicAdd(&sums[(u32)(it >> 32) & 255u], __uint_as_float((u32)it));
  }
  __syncthreads();
  int node = d * 256 + tid;
  if (node < N) asum[node] = sums[tid];
}

// ---------------- fused radix-select pass: hist + last-block pick ----------------
__global__ __launch_bounds__(256) void k_histpick(const float* __restrict__ asum,
                                                  u32* __restrict__ hist8, u32* __restrict__ done,
                                                  u32* __restrict__ sel, int N, int pass, int nblk) {
  __shared__ u32 lh[256];
  __shared__ u32 sres;
  __shared__ u32 s[256];
  int tid = threadIdx.x;
  lh[tid] = 0u;
  __syncthreads();
  u64 prefix = ((const u64*)sel)[0];   // written by previous kernel launch
  int shift = 56 - 8 * pass;
  int i = blockIdx.x * 256 + tid;
  if (i < N) {
    u64 k = key64(asum[i], i);
    bool ok = (pass == 0) || ((k >> (shift + 8)) == prefix);
    if (ok) atomicAdd(&lh[(u32)(k >> shift) & 255u], 1u);
  }
  __syncthreads();
  if (lh[tid]) atomicAdd(&hist8[pass * 256 + tid], lh[tid]);
  __syncthreads();   // drains this block's global atomics (vmcnt before barrier)
  if (tid == 0)
    sres = __hip_atomic_fetch_add(&done[pass], 1u, __ATOMIC_ACQ_REL, __HIP_MEMORY_SCOPE_AGENT);
  __syncthreads();
  if (sres == (u32)(nblk - 1)) {       // last block to finish: do the pick
    u32 krem = sel[2];
    u32 hv = __hip_atomic_load(&hist8[pass * 256 + (255 - tid)], __ATOMIC_RELAXED,
                               __HIP_MEMORY_SCOPE_AGENT);
    s[tid] = hv;
    __syncthreads();
    for (int o = 1; o < 256; o <<= 1) {
      u32 t = (tid >= o) ? s[tid - o] : 0u;
      __syncthreads();
      s[tid] += t;
      __syncthreads();
    }
    u32 cum = s[tid], prev = (tid > 0) ? s[tid - 1] : 0u;
    if (cum >= krem && prev < krem) {
      int dsel = 255 - tid;
      ((u64*)sel)[0] = (prefix << 8) | (u64)(u32)dsel;
      sel[2] = krem - prev;
    }
  }
}

// ---------------- node mask ----------------
__global__ __launch_bounds__(256) void k_node_mask(const float* __restrict__ asum,
                                                   const u32* __restrict__ sel,
                                                   u32* __restrict__ nm,
                                                   float* __restrict__ out_node, int N) {
  int i = blockIdx.x * 256 + threadIdx.x;
  if (i >= N) return;
  u64 T = ((const u64*)sel)[0];
  bool m = key64(asum[i], i) >= T;
  nm[i] = m ? 1u : 0u;
  out_node[i] = m ? 1.f : 0.f;
}

// ---------------- edge mask (no atomics) ----------------
__global__ __launch_bounds__(256) void k_edge_mask(const int* __restrict__ src, const int* __restrict__ tgt,
                                                   const u32* __restrict__ nm,
                                                   float* __restrict__ out_edge, int E, int EN) {
  int e = blockIdx.x * 256 + threadIdx.x;
  if (e >= EN) return;
  int s, t; edge_st(src, tgt, E, e, s, t);
  out_edge[e] = (nm[s] && nm[t]) ? 1.f : 0.f;
}

// ---------------- aggregate: wave per node over CSR, masked ----------------
__global__ __launch_bounds__(256) void k_aggregate(const u32* __restrict__ off,
                                                   const u64* __restrict__ csr,
                                                   const float* __restrict__ alpha,
                                                   const float* __restrict__ h,
                                                   const u32* __restrict__ nm,
                                                   float* __restrict__ out, int N) {
  int node = blockIdx.x * 4 + (threadIdx.x >> 6);
  int lane = threadIdx.x & 63;
  if (node >= N) return;
  float acc = 0.f;
  if (nm[node]) {
    u32 b = off[node], e2 = off[node + 1];
    for (u32 p = b; p < e2; ++p) {
      u32 s = (u32)csr[p];
      if (nm[s]) acc += alpha[p] * h[(size_t)s * OUT_C + lane];
    }
  }
  out[(size_t)node * OUT_C + lane] = acc;
}

// ---------------- launch ----------------
extern "C" void kernel_launch(void* const* d_in, const int* in_sizes, int n_in,
                              void* d_out, int out_size, void* d_ws, size_t ws_size,
                              hipStream_t stream) {
  const float* x   = (const float*)d_in[0];
  const float* w   = (const float*)d_in[1];
  const float* att = (const float*)d_in[2];
  const int*   ei  = (const int*)d_in[3];

  int N = in_sizes[0] / IN_C;
  int E = in_sizes[3] / 2;
  int EN = E + N;
  const int* src = ei;
  const int* tgt = ei + E;

  float* out      = (float*)d_out;
  float* out_edge = out + (size_t)N * OUT_C;
  float* out_node = out_edge + (size_t)EN;

  char* p = (char*)d_ws;
  auto alloc = [&](size_t bytes) -> char* {
    char* r = p;
    p += (bytes + 255) & ~(size_t)255;
    return r;
  };
  float* h     = (float*)alloc((size_t)N * OUT_C * 4);
  float* ai    = (float*)alloc((size_t)N * 4);
  float* aj    = (float*)alloc((size_t)N * 4);
  u64*   bufA  = (u64*)alloc((size_t)EN * 8);      // CSR items (tgt<<32|src)
  u64*   bufB  = (u64*)alloc((size_t)EN * 8);      // partition scratch
  float* alpha = (float*)alloc((size_t)EN * 4);    // alpha in CSR order
  u32*   offT  = (u32*)alloc((size_t)(N + 1) * 4);
  u32*   gh    = (u32*)alloc((size_t)RBINS * RB * 4);
  u32*   bsum  = (u32*)alloc(512 * 4);
  float* asum  = (float*)alloc((size_t)N * 4);
  u32*   nm    = (u32*)alloc((size_t)N * 4);
  u32*   hist8 = (u32*)alloc(2048 * 4);
  u32*   done  = (u32*)alloc(8 * 4);
  u32*   sel   = (u32*)alloc(256);

  u32 kSel = (u32)((N + 1) / 2);
  int chunk = (EN + RB - 1) / RB;
  int nGh = RBINS * RB;                // 131072
  int nScan = (nGh + 255) / 256;       // 512
  int gRow = (N + 63) / 64;
  int gN = (N + 255) / 256;
  int gE = (EN + 255) / 256;
  int gNode4 = (N + 3) / 4;

  k_init<<<8, 256, 0, stream>>>(hist8, done, sel, kSel);
  k_gemm<<<gRow, 256, 0, stream>>>(x, w, att, h, ai, aj, N);

  // ---- sort by target (coarse + fine) -> bufA = CSR ----
  k_rhist_t<<<RB, 256, 0, stream>>>(src, tgt, E, EN, chunk, gh);
  k_scanA<<<nScan, 256, 0, stream>>>(gh, gh, bsum, nGh);
  k_scanB<<<1, 512, 0, stream>>>(bsum, nScan);
  k_scanC<<<nScan, 256, 0, stream>>>(gh, bsum, nGh);
  k_rscatter_t<<<RB, 256, 0, stream>>>(src, tgt, E, EN, chunk, gh, bufB);
  k_rpass2<<<RBINS, 256, 0, stream>>>(bufB, bufA, gh, EN);
  k_runs<<<gE, 256, 0, stream>>>(bufA, offT, N, EN);

  k_softmax<<<gNode4, 256, 0, stream>>>(bufA, offT, ai, aj, alpha, N);

  // ---- coarse partition by source -> per-bucket LDS alpha_sum ----
  k_rhist_s<<<RB, 256, 0, stream>>>(bufA, EN, chunk, gh);
  k_scanA<<<nScan, 256, 0, stream>>>(gh, gh, bsum, nGh);
  k_scanB<<<1, 512, 0, stream>>>(bsum, nScan);
  k_scanC<<<nScan, 256, 0, stream>>>(gh, bsum, nGh);
  k_rscatter_s<<<RB, 256, 0, stream>>>(bufA, alpha, EN, chunk, gh, bufB);
  k_asum_acc<<<RBINS, 256, 0, stream>>>(bufB, gh, asum, N, EN);

  // ---- exact top-k threshold (8 fused hist+pick passes) ----
  for (int pass = 0; pass < 8; ++pass)
    k_histpick<<<gN, 256, 0, stream>>>(asum, hist8, done, sel, N, pass, gN);

  k_node_mask<<<gN, 256, 0, stream>>>(asum, sel, nm, out_node, N);
  k_edge_mask<<<gE, 256, 0, stream>>>(src, tgt, nm, out_edge, E, EN);
  k_aggregate<<<gNode4, 256, 0, stream>>>(offT, bufA, alpha, h, nm, out, N);
}

// Round 3
// 452.958 us; speedup vs baseline: 1.2870x; 1.1555x over previous
//
#include <hip/hip_runtime.h>
#include <stdint.h>

#define IN_C 128
#define OUT_C 64
#define NEG_SLOPE 0.2f
#define RB 256      // blocks in coarse-partition kernels
#define RBINS 512   // coarse bins (node>>8, node<131072)
#define STAGE 8192  // per-bucket LDS staging capacity (avg bucket ~3330)

typedef unsigned int u32;
typedef unsigned long long u64;

// ---------------- helpers ----------------
__device__ __forceinline__ u32 fenc(float f) {
  u32 u = __float_as_uint(f);
  return (u & 0x80000000u) ? ~u : (u | 0x80000000u);
}
__device__ __forceinline__ u64 key64(float v, int i) {
  return (((u64)fenc(v)) << 32) | (u64)(0xffffffffu - (u32)i);
}

// ---------------- init: zero select state ----------------
__global__ __launch_bounds__(256) void k_init(u32* hist8, u32* done, u32* sel, u32* cnt, u32 k) {
  int i = blockIdx.x * 256 + threadIdx.x;
  if (i < 2048) hist8[i] = 0u;
  if (i < 8) { done[i] = 0u; cnt[i] = 0u; }
  if (i == 0) { sel[0] = 0u; sel[1] = 0u; sel[2] = k; sel[3] = 0u; }
}

// ---------------- h = x @ W + fused ai/aj epilogue ----------------
__global__ __launch_bounds__(256) void k_gemm(const float* __restrict__ x,
                                              const float* __restrict__ w,
                                              const float* __restrict__ att,
                                              float* __restrict__ h,
                                              float* __restrict__ ai, float* __restrict__ aj,
                                              int N) {
  __shared__ float sw[IN_C * OUT_C];
  __shared__ float sx[64 * 65];
  int tid = threadIdx.x;
  int rbase = blockIdx.x * 64;

  for (int i = tid; i < (IN_C * OUT_C) / 4; i += 256)
    ((float4*)sw)[i] = ((const float4*)w)[i];

  int c0 = (tid & 7) * 8;
  int r0 = (tid >> 3) * 2;
  float acc[2][8];
#pragma unroll
  for (int i = 0; i < 2; i++)
#pragma unroll
    for (int j = 0; j < 8; j++) acc[i][j] = 0.f;

  for (int half = 0; half < 2; ++half) {
    __syncthreads();
    for (int i = tid; i < 4096; i += 256) {
      int kl = i & 63, r = i >> 6;
      int row = rbase + r;
      float v = 0.f;
      if (row < N) v = x[(size_t)row * IN_C + half * 64 + kl];
      sx[kl * 65 + r] = v;
    }
    __syncthreads();
#pragma unroll 2
    for (int kl = 0; kl < 64; ++kl) {
      float xr0 = sx[kl * 65 + r0];
      float xr1 = sx[kl * 65 + r0 + 1];
      const float* wp = &sw[(half * 64 + kl) * OUT_C + c0];
      float wv[8];
#pragma unroll
      for (int j = 0; j < 8; ++j) wv[j] = wp[j];
#pragma unroll
      for (int j = 0; j < 8; ++j) {
        acc[0][j] += xr0 * wv[j];
        acc[1][j] += xr1 * wv[j];
      }
    }
  }
  float pi0 = 0.f, pj0 = 0.f, pi1 = 0.f, pj1 = 0.f;
#pragma unroll
  for (int j = 0; j < 8; ++j) {
    float a0 = att[c0 + j], a1 = att[OUT_C + c0 + j];
    pi0 += acc[0][j] * a0; pj0 += acc[0][j] * a1;
    pi1 += acc[1][j] * a0; pj1 += acc[1][j] * a1;
  }
#pragma unroll
  for (int o = 1; o < 8; o <<= 1) {
    pi0 += __shfl_xor(pi0, o); pj0 += __shfl_xor(pj0, o);
    pi1 += __shfl_xor(pi1, o); pj1 += __shfl_xor(pj1, o);
  }
#pragma unroll
  for (int i = 0; i < 2; i++) {
    int row = rbase + r0 + i;
    if (row < N) {
      *(float4*)&h[(size_t)row * OUT_C + c0]     = make_float4(acc[i][0], acc[i][1], acc[i][2], acc[i][3]);
      *(float4*)&h[(size_t)row * OUT_C + c0 + 4] = make_float4(acc[i][4], acc[i][5], acc[i][6], acc[i][7]);
    }
  }
  if ((tid & 7) == 0) {
    int row = rbase + r0;
    if (row < N)     { ai[row] = pi0; aj[row] = pj0; }
    if (row + 1 < N) { ai[row + 1] = pi1; aj[row + 1] = pj1; }
  }
}

// ---------------- coarse hist by tgt>>8 (tgt-only read) ----------------
__global__ __launch_bounds__(256) void k_rhist_t(const int* __restrict__ tgt,
                                                 int E, int EN, int chunk, u32* __restrict__ gh) {
  __shared__ u32 lh[RBINS];
  int tid = threadIdx.x, b = blockIdx.x;
  for (int d = tid; d < RBINS; d += 256) lh[d] = 0u;
  __syncthreads();
  int lo = b * chunk, hi = min(lo + chunk, EN);
  for (int e = lo + tid; e < hi; e += 256) {
    int t = (e < E) ? tgt[e] : e - E;
    atomicAdd(&lh[((u32)t) >> 8], 1u);
  }
  __syncthreads();
  for (int d = tid; d < RBINS; d += 256) gh[d * RB + b] = lh[d];
}

// ---------------- generic 3-kernel exclusive scan (n <= 131072) ----------------
__global__ __launch_bounds__(256) void k_scanA(const u32* __restrict__ in, u32* __restrict__ out,
                                               u32* __restrict__ bsum, int n) {
  __shared__ u32 s[256];
  int i = blockIdx.x * 256 + threadIdx.x;
  u32 v = (i < n) ? in[i] : 0u;
  s[threadIdx.x] = v;
  __syncthreads();
  for (int o = 1; o < 256; o <<= 1) {
    u32 t = (threadIdx.x >= (unsigned)o) ? s[threadIdx.x - o] : 0u;
    __syncthreads();
    s[threadIdx.x] += t;
    __syncthreads();
  }
  if (i < n) out[i] = s[threadIdx.x] - v;
  if (threadIdx.x == 255) bsum[blockIdx.x] = s[255];
}

__global__ __launch_bounds__(512) void k_scanB(u32* __restrict__ bsum, int nb) {
  __shared__ u32 s[512];
  int tid = threadIdx.x;
  u32 v = (tid < nb) ? bsum[tid] : 0u;
  s[tid] = v;
  __syncthreads();
  for (int o = 1; o < 512; o <<= 1) {
    u32 t = (tid >= o) ? s[tid - o] : 0u;
    __syncthreads();
    s[tid] += t;
    __syncthreads();
  }
  if (tid < nb) bsum[tid] = s[tid] - v;
}

__global__ __launch_bounds__(256) void k_scanC(u32* __restrict__ out, const u32* __restrict__ bsum, int n) {
  int i = blockIdx.x * 256 + threadIdx.x;
  if (i < n) out[i] += bsum[blockIdx.x];
}

// ---------------- coarse scatter by tgt>>8: u32 items ((tgt&255)<<24 | src) ----------------
__global__ __launch_bounds__(256) void k_rscatter_t(const int* __restrict__ src, const int* __restrict__ tgt,
                                                    int E, int EN, int chunk,
                                                    const u32* __restrict__ gh, u32* __restrict__ bufB) {
  __shared__ u32 cnt[RBINS];
  int tid = threadIdx.x, b = blockIdx.x;
  for (int d = tid; d < RBINS; d += 256) cnt[d] = gh[d * RB + b];
  __syncthreads();
  int lo = b * chunk, hi = min(lo + chunk, EN);
  for (int e = lo + tid; e < hi; e += 256) {
    int s, t;
    if (e < E) { s = src[e]; t = tgt[e]; } else { s = t = e - E; }
    u32 p = atomicAdd(&cnt[((u32)t) >> 8], 1u);
    bufB[p] = (((u32)t & 255u) << 24) | (u32)s;
  }
}

// ---------------- fine partition within coarse bucket + direct CSR offsets ----------------
__global__ __launch_bounds__(256) void k_rpass2(const u32* __restrict__ in, u32* __restrict__ out,
                                                const u32* __restrict__ gh,
                                                u32* __restrict__ offT, int N, int EN) {
  __shared__ u32 hist[256];
  __shared__ u32 sc[256];
  __shared__ u32 stage[STAGE];
  int tid = threadIdx.x, d = blockIdx.x;
  u32 start = gh[d * RB];
  u32 end = (d < RBINS - 1) ? gh[(d + 1) * RB] : (u32)EN;
  int sz = (int)(end - start);
  hist[tid] = 0u;
  __syncthreads();
  for (u32 p = start + tid; p < end; p += 256)
    atomicAdd(&hist[in[p] >> 24], 1u);
  __syncthreads();
  u32 hv = hist[tid];
  sc[tid] = hv;
  __syncthreads();
  for (int o = 1; o < 256; o <<= 1) {
    u32 t = (tid >= o) ? sc[tid - o] : 0u;
    __syncthreads();
    sc[tid] += t;
    __syncthreads();
  }
  u32 excl = sc[tid] - hv;
  // CSR offsets: every node < N has >=1 incoming edge (self-loop)
  int node = (d << 8) + tid;
  if (node < N) offT[node] = start + excl;
  if (node == 0) offT[N] = (u32)EN;
  hist[tid] = excl;   // running cursor
  __syncthreads();
  bool staged = (sz <= STAGE);
  for (u32 p = start + tid; p < end; p += 256) {
    u32 it = in[p];
    u32 lp = atomicAdd(&hist[it >> 24], 1u);
    if (staged) stage[lp] = it;
    else out[start + lp] = it;
  }
  __syncthreads();
  if (staged)
    for (int i = tid; i < sz; i += 256) out[start + i] = stage[i];
}

// ---------------- per-node softmax (wave per node, zero atomics) ----------------
__global__ __launch_bounds__(256) void k_softmax(const u32* __restrict__ csr, const u32* __restrict__ off,
                                                 const float* __restrict__ ai, const float* __restrict__ aj,
                                                 float* __restrict__ alpha, int N) {
  int node = blockIdx.x * 4 + (threadIdx.x >> 6);
  int lane = threadIdx.x & 63;
  if (node >= N) return;
  u32 b = off[node], e2 = off[node + 1];
  float an = ai[node];
  float mx = -1e30f;
  for (u32 p = b + lane; p < e2; p += 64) {
    u32 s = csr[p] & 0xffffffu;
    float a = an + aj[s];
    a = a > 0.f ? a : NEG_SLOPE * a;
    alpha[p] = a;
    mx = fmaxf(mx, a);
  }
#pragma unroll
  for (int o = 32; o > 0; o >>= 1) mx = fmaxf(mx, __shfl_xor(mx, o));
  float sm = 0.f;
  for (u32 p = b + lane; p < e2; p += 64) {
    float v = expf(alpha[p] - mx);
    alpha[p] = v;
    sm += v;
  }
#pragma unroll
  for (int o = 32; o > 0; o >>= 1) sm += __shfl_xor(sm, o);
  float inv = 1.f / (sm + 1e-16f);
  for (u32 p = b + lane; p < e2; p += 64) alpha[p] *= inv;
}

// ---------------- coarse hist by src>>8 over CSR entries ----------------
__global__ __launch_bounds__(256) void k_rhist_s(const u32* __restrict__ csr, int EN, int chunk,
                                                 u32* __restrict__ gh) {
  __shared__ u32 lh[RBINS];
  int tid = threadIdx.x, b = blockIdx.x;
  for (int d = tid; d < RBINS; d += 256) lh[d] = 0u;
  __syncthreads();
  int lo = b * chunk, hi = min(lo + chunk, EN);
  for (int e = lo + tid; e < hi; e += 256)
    atomicAdd(&lh[(csr[e] & 0xffffffu) >> 8], 1u);
  __syncthreads();
  for (int d = tid; d < RBINS; d += 256) gh[d * RB + b] = lh[d];
}

// ---------------- coarse scatter by src>>8: u64 ((src&255)<<32 | alpha_bits) ----------------
__global__ __launch_bounds__(256) void k_rscatter_s(const u32* __restrict__ csr,
                                                    const float* __restrict__ alpha,
                                                    int EN, int chunk,
                                                    const u32* __restrict__ gh, u64* __restrict__ bufB) {
  __shared__ u32 cnt[RBINS];
  int tid = threadIdx.x, b = blockIdx.x;
  for (int d = tid; d < RBINS; d += 256) cnt[d] = gh[d * RB + b];
  __syncthreads();
  int lo = b * chunk, hi = min(lo + chunk, EN);
  for (int e = lo + tid; e < hi; e += 256) {
    u32 s = csr[e] & 0xffffffu;
    u32 p = atomicAdd(&cnt[s >> 8], 1u);
    bufB[p] = (((u64)(s & 255u)) << 32) | __float_as_uint(alpha[e]);
  }
}

// ---------------- per-bucket alpha_sum accumulation (LDS fp bins) ----------------
__global__ __launch_bounds__(256) void k_asum_acc(const u64* __restrict__ bufB,
                                                  const u32* __restrict__ gh,
                                                  float* __restrict__ asum, int N, int EN) {
  __shared__ float sums[256];
  int tid = threadIdx.x, d = blockIdx.x;
  u32 start = gh[d * RB];
  u32 end = (d < RBINS - 1) ? gh[(d + 1) * RB] : (u32)EN;
  sums[tid] = 0.f;
  __syncthreads();
  for (u32 p = start + tid; p < end; p += 256) {
    u64 it = bufB[p];
    atomicAdd(&sums[(u32)(it >> 32)], __uint_as_float((u32)it));
  }
  __syncthreads();
  int node = d * 256 + tid;
  if (node < N) asum[node] = sums[tid];
}

// ---------------- fused radix-select pass: hist + append + last-block pick ----------------
__global__ __launch_bounds__(256) void k_histpick(const float* __restrict__ asum,
                                                  const u32* __restrict__ list_in, const u32* __restrict__ cnt_in,
                                                  u32* __restrict__ list_out, u32* __restrict__ cnt_out,
                                                  u32* __restrict__ hist8, u32* __restrict__ done,
                                                  u32* __restrict__ sel, int N, int pass, int nblk) {
  __shared__ u32 lh[256];
  __shared__ u32 sres;
  __shared__ u32 s[256];
  int tid = threadIdx.x;
  lh[tid] = 0u;
  __syncthreads();
  u64 prefix = ((const u64*)sel)[0];
  int shift = 56 - 8 * pass;
  int n = list_in ? (int)*cnt_in : N;
  int i = blockIdx.x * 256 + tid;
  if (i < n) {
    int idx = list_in ? (int)list_in[i] : i;
    u64 k = key64(asum[idx], idx);
    bool ok = (pass == 0) || ((k >> (shift + 8)) == prefix);
    if (ok) {
      atomicAdd(&lh[(u32)(k >> shift) & 255u], 1u);
      if (list_out) {
        u32 p = atomicAdd(cnt_out, 1u);
        list_out[p] = (u32)idx;
      }
    }
  }
  __syncthreads();
  if (lh[tid]) atomicAdd(&hist8[pass * 256 + tid], lh[tid]);
  __syncthreads();
  if (tid == 0)
    sres = __hip_atomic_fetch_add(&done[pass], 1u, __ATOMIC_ACQ_REL, __HIP_MEMORY_SCOPE_AGENT);
  __syncthreads();
  if (sres == (u32)(nblk - 1)) {
    u32 krem = sel[2];
    u32 hv = __hip_atomic_load(&hist8[pass * 256 + (255 - tid)], __ATOMIC_RELAXED,
                               __HIP_MEMORY_SCOPE_AGENT);
    s[tid] = hv;
    __syncthreads();
    for (int o = 1; o < 256; o <<= 1) {
      u32 t = (tid >= o) ? s[tid - o] : 0u;
      __syncthreads();
      s[tid] += t;
      __syncthreads();
    }
    u32 cum = s[tid], prev = (tid > 0) ? s[tid - 1] : 0u;
    if (cum >= krem && prev < krem) {
      int dsel = 255 - tid;
      ((u64*)sel)[0] = (prefix << 8) | (u64)(u32)dsel;
      sel[2] = krem - prev;
    }
  }
}

// ---------------- node mask ----------------
__global__ __launch_bounds__(256) void k_node_mask(const float* __restrict__ asum,
                                                   const u32* __restrict__ sel,
                                                   u32* __restrict__ nm,
                                                   float* __restrict__ out_node, int N) {
  int i = blockIdx.x * 256 + threadIdx.x;
  if (i >= N) return;
  u64 T = ((const u64*)sel)[0];
  bool m = key64(asum[i], i) >= T;
  nm[i] = m ? 1u : 0u;
  out_node[i] = m ? 1.f : 0.f;
}

// ---------------- edge mask (no atomics) ----------------
__global__ __launch_bounds__(256) void k_edge_mask(const int* __restrict__ src, const int* __restrict__ tgt,
                                                   const u32* __restrict__ nm,
                                                   float* __restrict__ out_edge, int E, int EN) {
  int e = blockIdx.x * 256 + threadIdx.x;
  if (e >= EN) return;
  int s, t;
  if (e < E) { s = src[e]; t = tgt[e]; } else { s = t = e - E; }
  out_edge[e] = (nm[s] && nm[t]) ? 1.f : 0.f;
}

// ---------------- aggregate: wave per node, 4 neighbors x float4 channels ----------------
__global__ __launch_bounds__(256) void k_aggregate(const u32* __restrict__ off,
                                                   const u32* __restrict__ csr,
                                                   const float* __restrict__ alpha,
                                                   const float* __restrict__ h,
                                                   const u32* __restrict__ nm,
                                                   float* __restrict__ out, int N) {
  int node = blockIdx.x * 4 + (threadIdx.x >> 6);
  int lane = threadIdx.x & 63;
  int g = lane >> 4;        // neighbor subgroup 0..3
  int c = lane & 15;        // channel quad 0..15
  if (node >= N) return;
  float4 acc = make_float4(0.f, 0.f, 0.f, 0.f);
  if (nm[node]) {
    u32 b = off[node], e2 = off[node + 1];
    for (u32 p = b + g; p < e2; p += 4) {
      u32 s = csr[p] & 0xffffffu;
      if (nm[s]) {
        float a = alpha[p];
        float4 hv = *(const float4*)&h[(size_t)s * OUT_C + c * 4];
        acc.x += a * hv.x; acc.y += a * hv.y; acc.z += a * hv.z; acc.w += a * hv.w;
      }
    }
    // reduce across the 4 neighbor subgroups (lanes xor 16, 32)
#pragma unroll
    for (int o = 16; o < 64; o <<= 1) {
      acc.x += __shfl_xor(acc.x, o);
      acc.y += __shfl_xor(acc.y, o);
      acc.z += __shfl_xor(acc.z, o);
      acc.w += __shfl_xor(acc.w, o);
    }
  }
  if (g == 0)
    *(float4*)&out[(size_t)node * OUT_C + c * 4] = acc;
}

// ---------------- launch ----------------
extern "C" void kernel_launch(void* const* d_in, const int* in_sizes, int n_in,
                              void* d_out, int out_size, void* d_ws, size_t ws_size,
                              hipStream_t stream) {
  const float* x   = (const float*)d_in[0];
  const float* w   = (const float*)d_in[1];
  const float* att = (const float*)d_in[2];
  const int*   ei  = (const int*)d_in[3];

  int N = in_sizes[0] / IN_C;
  int E = in_sizes[3] / 2;
  int EN = E + N;
  const int* src = ei;
  const int* tgt = ei + E;

  float* out      = (float*)d_out;
  float* out_edge = out + (size_t)N * OUT_C;
  float* out_node = out_edge + (size_t)EN;

  char* p = (char*)d_ws;
  auto alloc = [&](size_t bytes) -> char* {
    char* r = p;
    p += (bytes + 255) & ~(size_t)255;
    return r;
  };
  float* h     = (float*)alloc((size_t)N * OUT_C * 4);
  float* ai    = (float*)alloc((size_t)N * 4);
  float* aj    = (float*)alloc((size_t)N * 4);
  u32*   bufA  = (u32*)alloc((size_t)EN * 4);      // CSR items ((tgt&255)<<24 | src)
  u64*   bufB  = (u64*)alloc((size_t)EN * 8);      // partition scratch (u32 or u64 view)
  float* alpha = (float*)alloc((size_t)EN * 4);    // alpha in CSR order
  u32*   offT  = (u32*)alloc((size_t)(N + 1) * 4);
  u32*   gh    = (u32*)alloc((size_t)RBINS * RB * 4);
  u32*   bsum  = (u32*)alloc(2048 * 4);
  float* asum  = (float*)alloc((size_t)N * 4);
  u32*   nm    = (u32*)alloc((size_t)N * 4);
  u32*   hist8 = (u32*)alloc(2048 * 4);
  u32*   done  = (u32*)alloc(8 * 4);
  u32*   cnt   = (u32*)alloc(8 * 4);
  u32*   sel   = (u32*)alloc(256);
  u32*   listA = (u32*)alloc((size_t)N * 4);
  u32*   listB = (u32*)alloc((size_t)N * 4);

  u32 kSel = (u32)((N + 1) / 2);
  int chunk = (EN + RB - 1) / RB;
  int nGh = RBINS * RB;                // 131072
  int nScan = (nGh + 255) / 256;       // 512
  int gRow = (N + 63) / 64;
  int gN = (N + 255) / 256;
  int gE = (EN + 255) / 256;
  int gNode4 = (N + 3) / 4;

  k_init<<<8, 256, 0, stream>>>(hist8, done, sel, cnt, kSel);
  k_gemm<<<gRow, 256, 0, stream>>>(x, w, att, h, ai, aj, N);

  // ---- partition by target (coarse + fine) -> bufA = CSR, offT direct ----
  k_rhist_t<<<RB, 256, 0, stream>>>(tgt, E, EN, chunk, gh);
  k_scanA<<<nScan, 256, 0, stream>>>(gh, gh, bsum, nGh);
  k_scanB<<<1, 512, 0, stream>>>(bsum, nScan);
  k_scanC<<<nScan, 256, 0, stream>>>(gh, bsum, nGh);
  k_rscatter_t<<<RB, 256, 0, stream>>>(src, tgt, E, EN, chunk, gh, (u32*)bufB);
  k_rpass2<<<RBINS, 256, 0, stream>>>((u32*)bufB, bufA, gh, offT, N, EN);

  k_softmax<<<gNode4, 256, 0, stream>>>(bufA, offT, ai, aj, alpha, N);

  // ---- coarse partition by source -> per-bucket LDS alpha_sum ----
  k_rhist_s<<<RB, 256, 0, stream>>>(bufA, EN, chunk, gh);
  k_scanA<<<nScan, 256, 0, stream>>>(gh, gh, bsum, nGh);
  k_scanB<<<1, 512, 0, stream>>>(bsum, nScan);
  k_scanC<<<nScan, 256, 0, stream>>>(gh, bsum, nGh);
  k_rscatter_s<<<RB, 256, 0, stream>>>(bufA, alpha, EN, chunk, gh, bufB);
  k_asum_acc<<<RBINS, 256, 0, stream>>>(bufB, gh, asum, N, EN);

  // ---- exact top-k threshold: 8 passes, candidate compaction from pass 1 ----
  // pass 0: full scan, no append. pass 1: full scan, append -> listA (cnt[1]).
  // pass p>=2: scan list, append -> ping-pong. pass 7: no append.
  k_histpick<<<gN, 256, 0, stream>>>(asum, nullptr, nullptr, nullptr, nullptr,
                                     hist8, done, sel, N, 0, gN);
  k_histpick<<<gN, 256, 0, stream>>>(asum, nullptr, nullptr, listA, &cnt[1],
                                     hist8, done, sel, N, 1, gN);
  u32* lin = listA; u32* lout = listB;
  for (int pass = 2; pass < 8; ++pass) {
    k_histpick<<<gN, 256, 0, stream>>>(asum, lin, &cnt[pass - 1],
                                       (pass < 7) ? lout : nullptr,
                                       (pass < 7) ? &cnt[pass] : nullptr,
                                       hist8, done, sel, N, pass, gN);
    u32* tswap = lin; lin = lout; lout = tswap;
  }

  k_node_mask<<<gN, 256, 0, stream>>>(asum, sel, nm, out_node, N);
  k_edge_mask<<<gE, 256, 0, stream>>>(src, tgt, nm, out_edge, E, EN);
  k_aggregate<<<gNode4, 256, 0, stream>>>(offT, bufA, alpha, h, nm, out, N);
}

// Round 4
// 426.879 us; speedup vs baseline: 1.3657x; 1.0611x over previous
//
#include <hip/hip_runtime.h>
#include <stdint.h>

#define IN_C 128
#define OUT_C 64
#define NEG_SLOPE 0.2f
#define RB 256      // blocks in coarse-partition kernels
#define RBINS 512   // coarse bins (node>>8, node<131072)
#define STAGE 8192  // per-bucket LDS staging capacity (avg bucket ~3330)
#define SXP 260     // sx row stride (floats): 2-way-only bank aliasing for b128 reads

typedef unsigned int u32;
typedef unsigned long long u64;

// ---------------- helpers ----------------
__device__ __forceinline__ u32 fenc(float f) {
  u32 u = __float_as_uint(f);
  return (u & 0x80000000u) ? ~u : (u | 0x80000000u);
}
__device__ __forceinline__ u64 key64(float v, int i) {
  return (((u64)fenc(v)) << 32) | (u64)(0xffffffffu - (u32)i);
}

// ---------------- init: zero select state ----------------
__global__ __launch_bounds__(256) void k_init(u32* hist8, u32* done, u32* sel, u32* cnt, u32 k) {
  int i = blockIdx.x * 256 + threadIdx.x;
  if (i < 2048) hist8[i] = 0u;
  if (i < 8) { done[i] = 0u; cnt[i] = 0u; }
  if (i == 0) { sel[0] = 0u; sel[1] = 0u; sel[2] = k; sel[3] = 0u; }
}

// ---------------- h = x @ W + fused ai/aj epilogue ----------------
// 256-row tile, thread = 8 rows x 8 cols (64 acc). K staged in 4 chunks of 32.
// LDS bytes/FMA = 1.0 (2x b128 sx + 2x b128 sw per 64 FMA) vs 2.5 in prior version.
__global__ __launch_bounds__(256) void k_gemm(const float* __restrict__ x,
                                              const float* __restrict__ w,
                                              const float* __restrict__ att,
                                              float* __restrict__ h,
                                              float* __restrict__ ai, float* __restrict__ aj,
                                              int N) {
  __shared__ float sw[IN_C * OUT_C];   // 32 KB, sw[k*64+c]
  __shared__ float sx[32 * SXP];       // 33.3 KB, sx[kl*SXP + row] (transposed)
  int tid = threadIdx.x;
  int rbase = blockIdx.x * 256;

  for (int i = tid; i < (IN_C * OUT_C) / 4; i += 256)
    ((float4*)sw)[i] = ((const float4*)w)[i];

  int c0 = (tid & 7) * 8;        // 8 col groups
  int r0 = (tid >> 3) * 8;       // 32 row groups x 8 rows = 256 rows
  float acc[8][8];
#pragma unroll
  for (int i = 0; i < 8; i++)
#pragma unroll
    for (int j = 0; j < 8; j++) acc[i][j] = 0.f;

  for (int kq = 0; kq < 4; ++kq) {
    __syncthreads();
    // stage x[rbase..rbase+255][kq*32..+31] -> sx[kl][row]; 128B/row coalesced loads
    for (int idx = tid; idx < 256 * 8; idx += 256) {
      int row = idx >> 3, j4 = idx & 7;
      int grow = rbase + row;
      float4 v = make_float4(0.f, 0.f, 0.f, 0.f);
      if (grow < N) v = *(const float4*)&x[(size_t)grow * IN_C + kq * 32 + j4 * 4];
      sx[(j4 * 4 + 0) * SXP + row] = v.x;
      sx[(j4 * 4 + 1) * SXP + row] = v.y;
      sx[(j4 * 4 + 2) * SXP + row] = v.z;
      sx[(j4 * 4 + 3) * SXP + row] = v.w;
    }
    __syncthreads();
#pragma unroll 4
    for (int kl = 0; kl < 32; ++kl) {
      int kg = kq * 32 + kl;
      float xr[8], wv[8];
      *(float4*)&xr[0] = *(const float4*)&sx[kl * SXP + r0];
      *(float4*)&xr[4] = *(const float4*)&sx[kl * SXP + r0 + 4];
      *(float4*)&wv[0] = *(const float4*)&sw[kg * OUT_C + c0];
      *(float4*)&wv[4] = *(const float4*)&sw[kg * OUT_C + c0 + 4];
#pragma unroll
      for (int i = 0; i < 8; ++i)
#pragma unroll
        for (int j = 0; j < 8; ++j)
          acc[i][j] += xr[i] * wv[j];
    }
  }

  // fused ai/aj: pi[i] = sum_c acc[i][c]*att[c], reduce over the 8 col-lane group
  float pi[8], pj[8];
#pragma unroll
  for (int i = 0; i < 8; ++i) { pi[i] = 0.f; pj[i] = 0.f; }
#pragma unroll
  for (int j = 0; j < 8; ++j) {
    float a0 = att[c0 + j], a1 = att[OUT_C + c0 + j];
#pragma unroll
    for (int i = 0; i < 8; ++i) {
      pi[i] += acc[i][j] * a0;
      pj[i] += acc[i][j] * a1;
    }
  }
#pragma unroll
  for (int o = 1; o < 8; o <<= 1) {
#pragma unroll
    for (int i = 0; i < 8; ++i) {
      pi[i] += __shfl_xor(pi[i], o);
      pj[i] += __shfl_xor(pj[i], o);
    }
  }
#pragma unroll
  for (int i = 0; i < 8; ++i) {
    int row = rbase + r0 + i;
    if (row < N) {
      *(float4*)&h[(size_t)row * OUT_C + c0]     = make_float4(acc[i][0], acc[i][1], acc[i][2], acc[i][3]);
      *(float4*)&h[(size_t)row * OUT_C + c0 + 4] = make_float4(acc[i][4], acc[i][5], acc[i][6], acc[i][7]);
      if ((tid & 7) == 0) { ai[row] = pi[i]; aj[row] = pj[i]; }
    }
  }
}

// ---------------- coarse hist by tgt>>8 (tgt-only read) ----------------
__global__ __launch_bounds__(256) void k_rhist_t(const int* __restrict__ tgt,
                                                 int E, int EN, int chunk, u32* __restrict__ gh) {
  __shared__ u32 lh[RBINS];
  int tid = threadIdx.x, b = blockIdx.x;
  for (int d = tid; d < RBINS; d += 256) lh[d] = 0u;
  __syncthreads();
  int lo = b * chunk, hi = min(lo + chunk, EN);
  for (int e = lo + tid; e < hi; e += 256) {
    int t = (e < E) ? tgt[e] : e - E;
    atomicAdd(&lh[((u32)t) >> 8], 1u);
  }
  __syncthreads();
  for (int d = tid; d < RBINS; d += 256) gh[d * RB + b] = lh[d];
}

// ---------------- generic 3-kernel exclusive scan (n <= 131072) ----------------
__global__ __launch_bounds__(256) void k_scanA(const u32* __restrict__ in, u32* __restrict__ out,
                                               u32* __restrict__ bsum, int n) {
  __shared__ u32 s[256];
  int i = blockIdx.x * 256 + threadIdx.x;
  u32 v = (i < n) ? in[i] : 0u;
  s[threadIdx.x] = v;
  __syncthreads();
  for (int o = 1; o < 256; o <<= 1) {
    u32 t = (threadIdx.x >= (unsigned)o) ? s[threadIdx.x - o] : 0u;
    __syncthreads();
    s[threadIdx.x] += t;
    __syncthreads();
  }
  if (i < n) out[i] = s[threadIdx.x] - v;
  if (threadIdx.x == 255) bsum[blockIdx.x] = s[255];
}

__global__ __launch_bounds__(512) void k_scanB(u32* __restrict__ bsum, int nb) {
  __shared__ u32 s[512];
  int tid = threadIdx.x;
  u32 v = (tid < nb) ? bsum[tid] : 0u;
  s[tid] = v;
  __syncthreads();
  for (int o = 1; o < 512; o <<= 1) {
    u32 t = (tid >= o) ? s[tid - o] : 0u;
    __syncthreads();
    s[tid] += t;
    __syncthreads();
  }
  if (tid < nb) bsum[tid] = s[tid] - v;
}

__global__ __launch_bounds__(256) void k_scanC(u32* __restrict__ out, const u32* __restrict__ bsum, int n) {
  int i = blockIdx.x * 256 + threadIdx.x;
  if (i < n) out[i] += bsum[blockIdx.x];
}

// ---------------- coarse scatter by tgt>>8: u32 items ((tgt&255)<<24 | src) ----------------
__global__ __launch_bounds__(256) void k_rscatter_t(const int* __restrict__ src, const int* __restrict__ tgt,
                                                    int E, int EN, int chunk,
                                                    const u32* __restrict__ gh, u32* __restrict__ bufB) {
  __shared__ u32 cnt[RBINS];
  int tid = threadIdx.x, b = blockIdx.x;
  for (int d = tid; d < RBINS; d += 256) cnt[d] = gh[d * RB + b];
  __syncthreads();
  int lo = b * chunk, hi = min(lo + chunk, EN);
  for (int e = lo + tid; e < hi; e += 256) {
    int s, t;
    if (e < E) { s = src[e]; t = tgt[e]; } else { s = t = e - E; }
    u32 p = atomicAdd(&cnt[((u32)t) >> 8], 1u);
    bufB[p] = (((u32)t & 255u) << 24) | (u32)s;
  }
}

// ---------------- fine partition within coarse bucket + direct CSR offsets ----------------
__global__ __launch_bounds__(256) void k_rpass2(const u32* __restrict__ in, u32* __restrict__ out,
                                                const u32* __restrict__ gh,
                                                u32* __restrict__ offT, int N, int EN) {
  __shared__ u32 hist[256];
  __shared__ u32 sc[256];
  __shared__ u32 stage[STAGE];
  int tid = threadIdx.x, d = blockIdx.x;
  u32 start = gh[d * RB];
  u32 end = (d < RBINS - 1) ? gh[(d + 1) * RB] : (u32)EN;
  int sz = (int)(end - start);
  hist[tid] = 0u;
  __syncthreads();
  for (u32 p = start + tid; p < end; p += 256)
    atomicAdd(&hist[in[p] >> 24], 1u);
  __syncthreads();
  u32 hv = hist[tid];
  sc[tid] = hv;
  __syncthreads();
  for (int o = 1; o < 256; o <<= 1) {
    u32 t = (tid >= o) ? sc[tid - o] : 0u;
    __syncthreads();
    sc[tid] += t;
    __syncthreads();
  }
  u32 excl = sc[tid] - hv;
  int node = (d << 8) + tid;
  if (node < N) offT[node] = start + excl;
  if (node == 0) offT[N] = (u32)EN;
  hist[tid] = excl;
  __syncthreads();
  bool staged = (sz <= STAGE);
  for (u32 p = start + tid; p < end; p += 256) {
    u32 it = in[p];
    u32 lp = atomicAdd(&hist[it >> 24], 1u);
    if (staged) stage[lp] = it;
    else out[start + lp] = it;
  }
  __syncthreads();
  if (staged)
    for (int i = tid; i < sz; i += 256) out[start + i] = stage[i];
}

// ---------------- per-node softmax: 16 lanes/node (deg~17), 4 nodes/wave ----------------
__global__ __launch_bounds__(256) void k_softmax(const u32* __restrict__ csr, const u32* __restrict__ off,
                                                 const float* __restrict__ ai, const float* __restrict__ aj,
                                                 float* __restrict__ alpha, int N) {
  int node = blockIdx.x * 16 + (threadIdx.x >> 4);
  int lane = threadIdx.x & 15;
  if (node >= N) return;
  u32 b = off[node], e2 = off[node + 1];
  float an = ai[node];
  float mx = -1e30f;
  for (u32 p = b + lane; p < e2; p += 16) {
    u32 s = csr[p] & 0xffffffu;
    float a = an + aj[s];
    a = a > 0.f ? a : NEG_SLOPE * a;
    alpha[p] = a;
    mx = fmaxf(mx, a);
  }
#pragma unroll
  for (int o = 8; o > 0; o >>= 1) mx = fmaxf(mx, __shfl_xor(mx, o));
  float sm = 0.f;
  for (u32 p = b + lane; p < e2; p += 16) {
    float v = expf(alpha[p] - mx);
    alpha[p] = v;
    sm += v;
  }
#pragma unroll
  for (int o = 8; o > 0; o >>= 1) sm += __shfl_xor(sm, o);
  float inv = 1.f / (sm + 1e-16f);
  for (u32 p = b + lane; p < e2; p += 16) alpha[p] *= inv;
}

// ---------------- coarse hist by src>>8 over CSR entries ----------------
__global__ __launch_bounds__(256) void k_rhist_s(const u32* __restrict__ csr, int EN, int chunk,
                                                 u32* __restrict__ gh) {
  __shared__ u32 lh[RBINS];
  int tid = threadIdx.x, b = blockIdx.x;
  for (int d = tid; d < RBINS; d += 256) lh[d] = 0u;
  __syncthreads();
  int lo = b * chunk, hi = min(lo + chunk, EN);
  for (int e = lo + tid; e < hi; e += 256)
    atomicAdd(&lh[(csr[e] & 0xffffffu) >> 8], 1u);
  __syncthreads();
  for (int d = tid; d < RBINS; d += 256) gh[d * RB + b] = lh[d];
}

// ---------------- coarse scatter by src>>8: u64 ((src&255)<<32 | alpha_bits) ----------------
__global__ __launch_bounds__(256) void k_rscatter_s(const u32* __restrict__ csr,
                                                    const float* __restrict__ alpha,
                                                    int EN, int chunk,
                                                    const u32* __restrict__ gh, u64* __restrict__ bufB) {
  __shared__ u32 cnt[RBINS];
  int tid = threadIdx.x, b = blockIdx.x;
  for (int d = tid; d < RBINS; d += 256) cnt[d] = gh[d * RB + b];
  __syncthreads();
  int lo = b * chunk, hi = min(lo + chunk, EN);
  for (int e = lo + tid; e < hi; e += 256) {
    u32 s = csr[e] & 0xffffffu;
    u32 p = atomicAdd(&cnt[s >> 8], 1u);
    bufB[p] = (((u64)(s & 255u)) << 32) | __float_as_uint(alpha[e]);
  }
}

// ---------------- per-bucket alpha_sum accumulation (LDS fp bins) ----------------
__global__ __launch_bounds__(256) void k_asum_acc(const u64* __restrict__ bufB,
                                                  const u32* __restrict__ gh,
                                                  float* __restrict__ asum, int N, int EN) {
  __shared__ float sums[256];
  int tid = threadIdx.x, d = blockIdx.x;
  u32 start = gh[d * RB];
  u32 end = (d < RBINS - 1) ? gh[(d + 1) * RB] : (u32)EN;
  sums[tid] = 0.f;
  __syncthreads();
  for (u32 p = start + tid; p < end; p += 256) {
    u64 it = bufB[p];
    atomicAdd(&sums[(u32)(it >> 32)], __uint_as_float((u32)it));
  }
  __syncthreads();
  int node = d * 256 + tid;
  if (node < N) asum[node] = sums[tid];
}

// ---------------- fused radix-select pass: hist + append + last-block pick ----------------
__global__ __launch_bounds__(256) void k_histpick(const float* __restrict__ asum,
                                                  const u32* __restrict__ list_in, const u32* __restrict__ cnt_in,
                                                  u32* __restrict__ list_out, u32* __restrict__ cnt_out,
                                                  u32* __restrict__ hist8, u32* __restrict__ done,
                                                  u32* __restrict__ sel, int N, int pass, int nblk) {
  __shared__ u32 lh[256];
  __shared__ u32 sres;
  __shared__ u32 s[256];
  int tid = threadIdx.x;
  lh[tid] = 0u;
  __syncthreads();
  u64 prefix = ((const u64*)sel)[0];
  int shift = 56 - 8 * pass;
  int n = list_in ? (int)*cnt_in : N;
  int i = blockIdx.x * 256 + tid;
  if (i < n) {
    int idx = list_in ? (int)list_in[i] : i;
    u64 k = key64(asum[idx], idx);
    bool ok = (pass == 0) || ((k >> (shift + 8)) == prefix);
    if (ok) {
      atomicAdd(&lh[(u32)(k >> shift) & 255u], 1u);
      if (list_out) {
        u32 p = atomicAdd(cnt_out, 1u);
        list_out[p] = (u32)idx;
      }
    }
  }
  __syncthreads();
  if (lh[tid]) atomicAdd(&hist8[pass * 256 + tid], lh[tid]);
  __syncthreads();
  if (tid == 0)
    sres = __hip_atomic_fetch_add(&done[pass], 1u, __ATOMIC_ACQ_REL, __HIP_MEMORY_SCOPE_AGENT);
  __syncthreads();
  if (sres == (u32)(nblk - 1)) {
    u32 krem = sel[2];
    u32 hv = __hip_atomic_load(&hist8[pass * 256 + (255 - tid)], __ATOMIC_RELAXED,
                               __HIP_MEMORY_SCOPE_AGENT);
    s[tid] = hv;
    __syncthreads();
    for (int o = 1; o < 256; o <<= 1) {
      u32 t = (tid >= o) ? s[tid - o] : 0u;
      __syncthreads();
      s[tid] += t;
      __syncthreads();
    }
    u32 cum = s[tid], prev = (tid > 0) ? s[tid - 1] : 0u;
    if (cum >= krem && prev < krem) {
      int dsel = 255 - tid;
      ((u64*)sel)[0] = (prefix << 8) | (u64)(u32)dsel;
      sel[2] = krem - prev;
    }
  }
}

// ---------------- node mask ----------------
__global__ __launch_bounds__(256) void k_node_mask(const float* __restrict__ asum,
                                                   const u32* __restrict__ sel,
                                                   u32* __restrict__ nm,
                                                   float* __restrict__ out_node, int N) {
  int i = blockIdx.x * 256 + threadIdx.x;
  if (i >= N) return;
  u64 T = ((const u64*)sel)[0];
  bool m = key64(asum[i], i) >= T;
  nm[i] = m ? 1u : 0u;
  out_node[i] = m ? 1.f : 0.f;
}

// ---------------- edge mask (no atomics) ----------------
__global__ __launch_bounds__(256) void k_edge_mask(const int* __restrict__ src, const int* __restrict__ tgt,
                                                   const u32* __restrict__ nm,
                                                   float* __restrict__ out_edge, int E, int EN) {
  int e = blockIdx.x * 256 + threadIdx.x;
  if (e >= EN) return;
  int s, t;
  if (e < E) { s = src[e]; t = tgt[e]; } else { s = t = e - E; }
  out_edge[e] = (nm[s] && nm[t]) ? 1.f : 0.f;
}

// ---------------- aggregate: wave per node, 4 neighbors x float4 channels ----------------
__global__ __launch_bounds__(256) void k_aggregate(const u32* __restrict__ off,
                                                   const u32* __restrict__ csr,
                                                   const float* __restrict__ alpha,
                                                   const float* __restrict__ h,
                                                   const u32* __restrict__ nm,
                                                   float* __restrict__ out, int N) {
  int node = blockIdx.x * 4 + (threadIdx.x >> 6);
  int lane = threadIdx.x & 63;
  int g = lane >> 4;
  int c = lane & 15;
  if (node >= N) return;
  float4 acc = make_float4(0.f, 0.f, 0.f, 0.f);
  if (nm[node]) {
    u32 b = off[node], e2 = off[node + 1];
    for (u32 p = b + g; p < e2; p += 4) {
      u32 s = csr[p] & 0xffffffu;
      if (nm[s]) {
        float a = alpha[p];
        float4 hv = *(const float4*)&h[(size_t)s * OUT_C + c * 4];
        acc.x += a * hv.x; acc.y += a * hv.y; acc.z += a * hv.z; acc.w += a * hv.w;
      }
    }
#pragma unroll
    for (int o = 16; o < 64; o <<= 1) {
      acc.x += __shfl_xor(acc.x, o);
      acc.y += __shfl_xor(acc.y, o);
      acc.z += __shfl_xor(acc.z, o);
      acc.w += __shfl_xor(acc.w, o);
    }
  }
  if (g == 0)
    *(float4*)&out[(size_t)node * OUT_C + c * 4] = acc;
}

// ---------------- launch ----------------
extern "C" void kernel_launch(void* const* d_in, const int* in_sizes, int n_in,
                              void* d_out, int out_size, void* d_ws, size_t ws_size,
                              hipStream_t stream) {
  const float* x   = (const float*)d_in[0];
  const float* w   = (const float*)d_in[1];
  const float* att = (const float*)d_in[2];
  const int*   ei  = (const int*)d_in[3];

  int N = in_sizes[0] / IN_C;
  int E = in_sizes[3] / 2;
  int EN = E + N;
  const int* src = ei;
  const int* tgt = ei + E;

  float* out      = (float*)d_out;
  float* out_edge = out + (size_t)N * OUT_C;
  float* out_node = out_edge + (size_t)EN;

  char* p = (char*)d_ws;
  auto alloc = [&](size_t bytes) -> char* {
    char* r = p;
    p += (bytes + 255) & ~(size_t)255;
    return r;
  };
  float* h     = (float*)alloc((size_t)N * OUT_C * 4);
  float* ai    = (float*)alloc((size_t)N * 4);
  float* aj    = (float*)alloc((size_t)N * 4);
  u32*   bufA  = (u32*)alloc((size_t)EN * 4);
  u64*   bufB  = (u64*)alloc((size_t)EN * 8);
  float* alpha = (float*)alloc((size_t)EN * 4);
  u32*   offT  = (u32*)alloc((size_t)(N + 1) * 4);
  u32*   gh    = (u32*)alloc((size_t)RBINS * RB * 4);
  u32*   bsum  = (u32*)alloc(2048 * 4);
  float* asum  = (float*)alloc((size_t)N * 4);
  u32*   nm    = (u32*)alloc((size_t)N * 4);
  u32*   hist8 = (u32*)alloc(2048 * 4);
  u32*   done  = (u32*)alloc(8 * 4);
  u32*   cnt   = (u32*)alloc(8 * 4);
  u32*   sel   = (u32*)alloc(256);
  u32*   listA = (u32*)alloc((size_t)N * 4);
  u32*   listB = (u32*)alloc((size_t)N * 4);

  u32 kSel = (u32)((N + 1) / 2);
  int chunk = (EN + RB - 1) / RB;
  int nGh = RBINS * RB;
  int nScan = (nGh + 255) / 256;
  int gRow = (N + 255) / 256;          // 256-row GEMM tiles
  int gN = (N + 255) / 256;
  int gE = (EN + 255) / 256;
  int gNode4 = (N + 3) / 4;
  int gNode16 = (N + 15) / 16;

  k_init<<<8, 256, 0, stream>>>(hist8, done, sel, cnt, kSel);
  k_gemm<<<gRow, 256, 0, stream>>>(x, w, att, h, ai, aj, N);

  k_rhist_t<<<RB, 256, 0, stream>>>(tgt, E, EN, chunk, gh);
  k_scanA<<<nScan, 256, 0, stream>>>(gh, gh, bsum, nGh);
  k_scanB<<<1, 512, 0, stream>>>(bsum, nScan);
  k_scanC<<<nScan, 256, 0, stream>>>(gh, bsum, nGh);
  k_rscatter_t<<<RB, 256, 0, stream>>>(src, tgt, E, EN, chunk, gh, (u32*)bufB);
  k_rpass2<<<RBINS, 256, 0, stream>>>((u32*)bufB, bufA, gh, offT, N, EN);

  k_softmax<<<gNode16, 256, 0, stream>>>(bufA, offT, ai, aj, alpha, N);

  k_rhist_s<<<RB, 256, 0, stream>>>(bufA, EN, chunk, gh);
  k_scanA<<<nScan, 256, 0, stream>>>(gh, gh, bsum, nGh);
  k_scanB<<<1, 512, 0, stream>>>(bsum, nScan);
  k_scanC<<<nScan, 256, 0, stream>>>(gh, bsum, nGh);
  k_rscatter_s<<<RB, 256, 0, stream>>>(bufA, alpha, EN, chunk, gh, bufB);
  k_asum_acc<<<RBINS, 256, 0, stream>>>(bufB, gh, asum, N, EN);

  k_histpick<<<gN, 256, 0, stream>>>(asum, nullptr, nullptr, nullptr, nullptr,
                                     hist8, done, sel, N, 0, gN);
  k_histpick<<<gN, 256, 0, stream>>>(asum, nullptr, nullptr, listA, &cnt[1],
                                     hist8, done, sel, N, 1, gN);
  u32* lin = listA; u32* lout = listB;
  for (int pass = 2; pass < 8; ++pass) {
    k_histpick<<<gN, 256, 0, stream>>>(asum, lin, &cnt[pass - 1],
                                       (pass < 7) ? lout : nullptr,
                                       (pass < 7) ? &cnt[pass] : nullptr,
                                       hist8, done, sel, N, pass, gN);
    u32* tswap = lin; lin = lout; lout = tswap;
  }

  k_node_mask<<<gN, 256, 0, stream>>>(asum, sel, nm, out_node, N);
  k_edge_mask<<<gE, 256, 0, stream>>>(src, tgt, nm, out_edge, E, EN);
  k_aggregate<<<gNode4, 256, 0, stream>>>(offT, bufA, alpha, h, nm, out, N);
}

// Round 6
// 376.102 us; speedup vs baseline: 1.5501x; 1.1350x over previous
//
#include <hip/hip_runtime.h>
#include <stdint.h>

#define IN_C 128
#define OUT_C 64
#define NEG_SLOPE 0.2f
#define RB 256      // blocks in coarse-partition kernels
#define RBINS 512   // coarse bins (node>>8, node<131072)
#define STAGE 8192  // per-bucket LDS staging capacity (avg bucket ~3330)
#define SXP 260     // sx row stride (floats)
#define NGH (RBINS * RB)       // 131072 (tgt histogram)
#define NGHS (RBINS * RBINS)   // 262144 (src histogram: sbin*512 + tgt-bucket-block)

typedef unsigned int u32;
typedef unsigned long long u64;

// ---------------- helpers ----------------
__device__ __forceinline__ u32 fenc(float f) {
  u32 u = __float_as_uint(f);
  return (u & 0x80000000u) ? ~u : (u | 0x80000000u);
}
__device__ __forceinline__ u64 key64(float v, int i) {
  return (((u64)fenc(v)) << 32) | (u64)(0xffffffffu - (u32)i);
}

// ---------------- init ----------------
__global__ __launch_bounds__(256) void k_init(u32* hist8, u32* done, u32* sel, u32* cnt, u32 k) {
  int i = blockIdx.x * 256 + threadIdx.x;
  if (i < 2048) hist8[i] = 0u;
  if (i < 8) { done[i] = 0u; cnt[i] = 0u; }
  if (i == 0) { sel[0] = 0u; sel[1] = 0u; sel[2] = k; sel[3] = 0u; }
}

// ---------------- h = x @ W + fused ai/aj epilogue (256-row tile, 8x8/thread) ----------------
__global__ __launch_bounds__(256) void k_gemm(const float* __restrict__ x,
                                              const float* __restrict__ w,
                                              const float* __restrict__ att,
                                              float* __restrict__ h,
                                              float* __restrict__ ai, float* __restrict__ aj,
                                              int N) {
  __shared__ float sw[IN_C * OUT_C];
  __shared__ float sx[32 * SXP];
  int tid = threadIdx.x;
  int rbase = blockIdx.x * 256;

  for (int i = tid; i < (IN_C * OUT_C) / 4; i += 256)
    ((float4*)sw)[i] = ((const float4*)w)[i];

  int c0 = (tid & 7) * 8;
  int r0 = (tid >> 3) * 8;
  float acc[8][8];
#pragma unroll
  for (int i = 0; i < 8; i++)
#pragma unroll
    for (int j = 0; j < 8; j++) acc[i][j] = 0.f;

  for (int kq = 0; kq < 4; ++kq) {
    __syncthreads();
    for (int idx = tid; idx < 256 * 8; idx += 256) {
      int row = idx >> 3, j4 = idx & 7;
      int grow = rbase + row;
      float4 v = make_float4(0.f, 0.f, 0.f, 0.f);
      if (grow < N) v = *(const float4*)&x[(size_t)grow * IN_C + kq * 32 + j4 * 4];
      sx[(j4 * 4 + 0) * SXP + row] = v.x;
      sx[(j4 * 4 + 1) * SXP + row] = v.y;
      sx[(j4 * 4 + 2) * SXP + row] = v.z;
      sx[(j4 * 4 + 3) * SXP + row] = v.w;
    }
    __syncthreads();
#pragma unroll 4
    for (int kl = 0; kl < 32; ++kl) {
      int kg = kq * 32 + kl;
      float xr[8], wv[8];
      *(float4*)&xr[0] = *(const float4*)&sx[kl * SXP + r0];
      *(float4*)&xr[4] = *(const float4*)&sx[kl * SXP + r0 + 4];
      *(float4*)&wv[0] = *(const float4*)&sw[kg * OUT_C + c0];
      *(float4*)&wv[4] = *(const float4*)&sw[kg * OUT_C + c0 + 4];
#pragma unroll
      for (int i = 0; i < 8; ++i)
#pragma unroll
        for (int j = 0; j < 8; ++j)
          acc[i][j] += xr[i] * wv[j];
    }
  }

  float pi[8], pj[8];
#pragma unroll
  for (int i = 0; i < 8; ++i) { pi[i] = 0.f; pj[i] = 0.f; }
#pragma unroll
  for (int j = 0; j < 8; ++j) {
    float a0 = att[c0 + j], a1 = att[OUT_C + c0 + j];
#pragma unroll
    for (int i = 0; i < 8; ++i) {
      pi[i] += acc[i][j] * a0;
      pj[i] += acc[i][j] * a1;
    }
  }
#pragma unroll
  for (int o = 1; o < 8; o <<= 1) {
#pragma unroll
    for (int i = 0; i < 8; ++i) {
      pi[i] += __shfl_xor(pi[i], o);
      pj[i] += __shfl_xor(pj[i], o);
    }
  }
#pragma unroll
  for (int i = 0; i < 8; ++i) {
    int row = rbase + r0 + i;
    if (row < N) {
      *(float4*)&h[(size_t)row * OUT_C + c0]     = make_float4(acc[i][0], acc[i][1], acc[i][2], acc[i][3]);
      *(float4*)&h[(size_t)row * OUT_C + c0 + 4] = make_float4(acc[i][4], acc[i][5], acc[i][6], acc[i][7]);
      if ((tid & 7) == 0) { ai[row] = pi[i]; aj[row] = pj[i]; }
    }
  }
}

// ---------------- coarse hist by tgt>>8 (raw order; matches k_rscatter_t iteration) ----------------
__global__ __launch_bounds__(256) void k_rhist_t(const int* __restrict__ tgt,
                                                 int E, int EN, int chunk, u32* __restrict__ gh) {
  __shared__ u32 lh[RBINS];
  int tid = threadIdx.x, b = blockIdx.x;
  for (int d = tid; d < RBINS; d += 256) lh[d] = 0u;
  __syncthreads();
  int lo = b * chunk, hi = min(lo + chunk, EN);
  for (int e = lo + tid; e < hi; e += 256) {
    int t = (e < E) ? tgt[e] : e - E;
    atomicAdd(&lh[((u32)t) >> 8], 1u);
  }
  __syncthreads();
  for (int d = tid; d < RBINS; d += 256) gh[d * RB + b] = lh[d];
}

// ---------------- generic 3-kernel exclusive scan (n <= 262144) ----------------
__global__ __launch_bounds__(256) void k_scanA(const u32* __restrict__ in, u32* __restrict__ out,
                                               u32* __restrict__ bsum, int n) {
  __shared__ u32 s[256];
  int i = blockIdx.x * 256 + threadIdx.x;
  u32 v = (i < n) ? in[i] : 0u;
  s[threadIdx.x] = v;
  __syncthreads();
  for (int o = 1; o < 256; o <<= 1) {
    u32 t = (threadIdx.x >= (unsigned)o) ? s[threadIdx.x - o] : 0u;
    __syncthreads();
    s[threadIdx.x] += t;
    __syncthreads();
  }
  if (i < n) out[i] = s[threadIdx.x] - v;
  if (threadIdx.x == 255) bsum[blockIdx.x] = s[255];
}

__global__ __launch_bounds__(1024) void k_scanB(u32* __restrict__ bsum, int nb) {
  __shared__ u32 s[1024];
  int tid = threadIdx.x;
  u32 v = (tid < nb) ? bsum[tid] : 0u;
  s[tid] = v;
  __syncthreads();
  for (int o = 1; o < 1024; o <<= 1) {
    u32 t = (tid >= o) ? s[tid - o] : 0u;
    __syncthreads();
    s[tid] += t;
    __syncthreads();
  }
  if (tid < nb) bsum[tid] = s[tid] - v;
}

__global__ __launch_bounds__(256) void k_scanC(u32* __restrict__ out, const u32* __restrict__ bsum, int n) {
  int i = blockIdx.x * 256 + threadIdx.x;
  if (i < n) out[i] += bsum[blockIdx.x];
}

// ---------------- coarse scatter by tgt>>8: u32 items ((tgt&255)<<24 | src) ----------------
__global__ __launch_bounds__(256) void k_rscatter_t(const int* __restrict__ src, const int* __restrict__ tgt,
                                                    int E, int EN, int chunk,
                                                    const u32* __restrict__ gh, u32* __restrict__ bufB) {
  __shared__ u32 cnt[RBINS];
  int tid = threadIdx.x, b = blockIdx.x;
  for (int d = tid; d < RBINS; d += 256) cnt[d] = gh[d * RB + b];
  __syncthreads();
  int lo = b * chunk, hi = min(lo + chunk, EN);
  for (int e = lo + tid; e < hi; e += 256) {
    int s, t;
    if (e < E) { s = src[e]; t = tgt[e]; } else { s = t = e - E; }
    u32 p = atomicAdd(&cnt[((u32)t) >> 8], 1u);
    bufB[p] = (((u32)t & 255u) << 24) | (u32)s;
  }
}

// ---------------- fine partition within coarse bucket + CSR offsets + fused src>>8 hist ----
// Block d processes tgt-bucket d's CSR range; counts src>>8 into ghs[sbin*RBINS + d].
// k_rscatter_s iterates the SAME per-bucket ranges -> per-(bin,block) counts consistent.
__global__ __launch_bounds__(256) void k_rpass2(const u32* __restrict__ in, u32* __restrict__ out,
                                                const u32* __restrict__ gh, u32* __restrict__ ghs,
                                                u32* __restrict__ offT, int N, int EN) {
  __shared__ u32 hist[256];
  __shared__ u32 sc[256];
  __shared__ u32 lhs[RBINS];
  __shared__ u32 stage[STAGE];
  int tid = threadIdx.x, d = blockIdx.x;
  u32 start = gh[d * RB];
  u32 end = (d < RBINS - 1) ? gh[(d + 1) * RB] : (u32)EN;
  int sz = (int)(end - start);
  hist[tid] = 0u;
  for (int dd = tid; dd < RBINS; dd += 256) lhs[dd] = 0u;
  __syncthreads();
  for (u32 p = start + tid; p < end; p += 256) {
    u32 it = in[p];
    atomicAdd(&hist[it >> 24], 1u);
    atomicAdd(&lhs[(it & 0xffffffu) >> 8], 1u);
  }
  __syncthreads();
  for (int dd = tid; dd < RBINS; dd += 256) ghs[dd * RBINS + d] = lhs[dd];
  u32 hv = hist[tid];
  sc[tid] = hv;
  __syncthreads();
  for (int o = 1; o < 256; o <<= 1) {
    u32 t = (tid >= o) ? sc[tid - o] : 0u;
    __syncthreads();
    sc[tid] += t;
    __syncthreads();
  }
  u32 excl = sc[tid] - hv;
  int node = (d << 8) + tid;
  if (node < N) offT[node] = start + excl;
  if (node == 0) offT[N] = (u32)EN;
  hist[tid] = excl;
  __syncthreads();
  bool staged = (sz <= STAGE);
  for (u32 p = start + tid; p < end; p += 256) {
    u32 it = in[p];
    u32 lp = atomicAdd(&hist[it >> 24], 1u);
    if (staged) stage[lp] = it;
    else out[start + lp] = it;
  }
  __syncthreads();
  if (staged)
    for (int i = tid; i < sz; i += 256) out[start + i] = stage[i];
}

// ---------------- per-node softmax: 16 lanes/node ----------------
__global__ __launch_bounds__(256) void k_softmax(const u32* __restrict__ csr, const u32* __restrict__ off,
                                                 const float* __restrict__ ai, const float* __restrict__ aj,
                                                 float* __restrict__ alpha, int N) {
  int node = blockIdx.x * 16 + (threadIdx.x >> 4);
  int lane = threadIdx.x & 15;
  if (node >= N) return;
  u32 b = off[node], e2 = off[node + 1];
  float an = ai[node];
  float mx = -1e30f;
  for (u32 p = b + lane; p < e2; p += 16) {
    u32 s = csr[p] & 0xffffffu;
    float a = an + aj[s];
    a = a > 0.f ? a : NEG_SLOPE * a;
    alpha[p] = a;
    mx = fmaxf(mx, a);
  }
#pragma unroll
  for (int o = 8; o > 0; o >>= 1) mx = fmaxf(mx, __shfl_xor(mx, o));
  float sm = 0.f;
  for (u32 p = b + lane; p < e2; p += 16) {
    float v = expf(alpha[p] - mx);
    alpha[p] = v;
    sm += v;
  }
#pragma unroll
  for (int o = 8; o > 0; o >>= 1) sm += __shfl_xor(sm, o);
  float inv = 1.f / (sm + 1e-16f);
  for (u32 p = b + lane; p < e2; p += 16) alpha[p] *= inv;
}

// ---------------- scatter by src>>8 over the SAME per-bucket ranges as k_rpass2 ----------------
__global__ __launch_bounds__(256) void k_rscatter_s(const u32* __restrict__ csr,
                                                    const float* __restrict__ alpha,
                                                    const u32* __restrict__ gh, const u32* __restrict__ ghs,
                                                    u64* __restrict__ bufB, int EN) {
  __shared__ u32 cnt[RBINS];
  int tid = threadIdx.x, d = blockIdx.x;
  for (int dd = tid; dd < RBINS; dd += 256) cnt[dd] = ghs[dd * RBINS + d];
  __syncthreads();
  u32 start = gh[d * RB];
  u32 end = (d < RBINS - 1) ? gh[(d + 1) * RB] : (u32)EN;
  for (u32 e = start + tid; e < end; e += 256) {
    u32 s = csr[e] & 0xffffffu;
    u32 p = atomicAdd(&cnt[s >> 8], 1u);
    bufB[p] = (((u64)(s & 255u)) << 32) | __float_as_uint(alpha[e]);
  }
}

// ---------------- per-bucket alpha_sum accumulation (LDS fp bins) ----------------
__global__ __launch_bounds__(256) void k_asum_acc(const u64* __restrict__ bufB,
                                                  const u32* __restrict__ ghs,
                                                  float* __restrict__ asum, int N, int EN) {
  __shared__ float sums[256];
  int tid = threadIdx.x, d = blockIdx.x;
  u32 start = ghs[d * RBINS];
  u32 end = (d < RBINS - 1) ? ghs[(d + 1) * RBINS] : (u32)EN;
  sums[tid] = 0.f;
  __syncthreads();
  for (u32 p = start + tid; p < end; p += 256) {
    u64 it = bufB[p];
    atomicAdd(&sums[(u32)(it >> 32)], __uint_as_float((u32)it));
  }
  __syncthreads();
  int node = d * 256 + tid;
  if (node < N) asum[node] = sums[tid];
}

// ---------------- fused radix-select pass: hist + append + last-block pick ----------------
__global__ __launch_bounds__(256) void k_histpick(const float* __restrict__ asum,
                                                  const u32* __restrict__ list_in, const u32* __restrict__ cnt_in,
                                                  u32* __restrict__ list_out, u32* __restrict__ cnt_out,
                                                  u32* __restrict__ hist8, u32* __restrict__ done,
                                                  u32* __restrict__ sel, int N, int pass, int nblk) {
  __shared__ u32 lh[256];
  __shared__ u32 sres;
  __shared__ u32 s[256];
  int tid = threadIdx.x;
  lh[tid] = 0u;
  __syncthreads();
  u64 prefix = ((const u64*)sel)[0];
  int shift = 56 - 8 * pass;
  int n = list_in ? (int)*cnt_in : N;
  int i = blockIdx.x * 256 + tid;
  if (i < n) {
    int idx = list_in ? (int)list_in[i] : i;
    u64 k = key64(asum[idx], idx);
    bool ok = (pass == 0) || ((k >> (shift + 8)) == prefix);
    if (ok) {
      atomicAdd(&lh[(u32)(k >> shift) & 255u], 1u);
      if (list_out) {
        u32 p = atomicAdd(cnt_out, 1u);
        list_out[p] = (u32)idx;
      }
    }
  }
  __syncthreads();
  if (lh[tid]) atomicAdd(&hist8[pass * 256 + tid], lh[tid]);
  __syncthreads();
  if (tid == 0)
    sres = __hip_atomic_fetch_add(&done[pass], 1u, __ATOMIC_ACQ_REL, __HIP_MEMORY_SCOPE_AGENT);
  __syncthreads();
  if (sres == (u32)(nblk - 1)) {
    u32 krem = sel[2];
    u32 hv = __hip_atomic_load(&hist8[pass * 256 + (255 - tid)], __ATOMIC_RELAXED,
                               __HIP_MEMORY_SCOPE_AGENT);
    s[tid] = hv;
    __syncthreads();
    for (int o = 1; o < 256; o <<= 1) {
      u32 t = (tid >= o) ? s[tid - o] : 0u;
      __syncthreads();
      s[tid] += t;
      __syncthreads();
    }
    u32 cum = s[tid], prev = (tid > 0) ? s[tid - 1] : 0u;
    if (cum >= krem && prev < krem) {
      int dsel = 255 - tid;
      ((u64*)sel)[0] = (prefix << 8) | (u64)(u32)dsel;
      sel[2] = krem - prev;
    }
  }
}

// ---------------- finish select: fenc fixed after 4 passes; rank-select index ties ----------------
__global__ __launch_bounds__(256) void k_finish(const float* __restrict__ asum,
                                                const u32* __restrict__ list, const u32* __restrict__ cntp,
                                                u32* __restrict__ sel) {
  __shared__ u64 keys[2048];
  __shared__ u32 cc;
  int tid = threadIdx.x;
  if (tid == 0) cc = 0u;
  __syncthreads();
  int n = (int)*cntp;
  u32 fsel = (u32)((const u64*)sel)[0];   // fully-determined fenc value
  u32 krem = sel[2];
  for (int i = tid; i < n; i += 256) {
    int idx = (int)list[i];
    u64 k = key64(asum[idx], idx);
    if ((u32)(k >> 32) == fsel) {
      u32 p = atomicAdd(&cc, 1u);
      if (p < 2048) keys[p] = k;
    }
  }
  __syncthreads();
  int C = (int)min(cc, 2048u);
  for (int i = tid; i < C; i += 256) {
    u64 k = keys[i];
    u32 rank = 0;
    for (int j = 0; j < C; ++j)
      if (keys[j] > k) rank++;
    if (rank == krem - 1) ((u64*)sel)[0] = k;   // full 64-bit threshold key
  }
}

// ---------------- node mask ----------------
__global__ __launch_bounds__(256) void k_node_mask(const float* __restrict__ asum,
                                                   const u32* __restrict__ sel,
                                                   u32* __restrict__ nm,
                                                   float* __restrict__ out_node, int N) {
  int i = blockIdx.x * 256 + threadIdx.x;
  if (i >= N) return;
  u64 T = ((const u64*)sel)[0];
  bool m = key64(asum[i], i) >= T;
  nm[i] = m ? 1u : 0u;
  out_node[i] = m ? 1.f : 0.f;
}

// ---------------- fused: raw-order edge mask + CSR-order premasked (src,alpha) pairs ----------------
__global__ __launch_bounds__(256) void k_mask(const int* __restrict__ src, const int* __restrict__ tgt,
                                              const u32* __restrict__ nm,
                                              const u32* __restrict__ csr, const float* __restrict__ alpha,
                                              float* __restrict__ out_edge, u64* __restrict__ pair,
                                              int E, int EN) {
  int e = blockIdx.x * 256 + threadIdx.x;
  if (e >= EN) return;
  int s, t;
  if (e < E) { s = src[e]; t = tgt[e]; } else { s = t = e - E; }
  out_edge[e] = (nm[s] && nm[t]) ? 1.f : 0.f;
  u32 sp = csr[e] & 0xffffffu;   // e doubles as CSR slot id (full range covered)
  u32 ab = nm[sp] ? __float_as_uint(alpha[e]) : 0u;
  pair[e] = (((u64)sp) << 32) | ab;
}

// ---------------- aggregate: branchless, 4-slot software pipeline per group ----------------
__global__ __launch_bounds__(256) void k_aggregate(const u32* __restrict__ off,
                                                   const u64* __restrict__ pair,
                                                   const float* __restrict__ h,
                                                   const u32* __restrict__ nm,
                                                   float* __restrict__ out, int N) {
  int node = blockIdx.x * 4 + (threadIdx.x >> 6);
  int lane = threadIdx.x & 63;
  int g = lane >> 4;        // 4 edge groups
  int c = lane & 15;        // channel quad
  if (node >= N) return;
  float4 acc = make_float4(0.f, 0.f, 0.f, 0.f);
  if (nm[node]) {
    u32 b = off[node], e2 = off[node + 1];
    for (u32 p0 = b; p0 < e2; p0 += 16) {
      u64 pr[4];
      float av[4];
      u32 sv[4];
#pragma unroll
      for (int q = 0; q < 4; ++q) {
        u32 p = p0 + q * 4 + (u32)g;
        bool ok = p < e2;
        pr[q] = pair[ok ? p : b];
        av[q] = ok ? __uint_as_float((u32)pr[q]) : 0.f;
        sv[q] = (u32)(pr[q] >> 32);
      }
      float4 hv[4];
#pragma unroll
      for (int q = 0; q < 4; ++q)
        hv[q] = *(const float4*)&h[(size_t)sv[q] * OUT_C + c * 4];
#pragma unroll
      for (int q = 0; q < 4; ++q) {
        acc.x += av[q] * hv[q].x;
        acc.y += av[q] * hv[q].y;
        acc.z += av[q] * hv[q].z;
        acc.w += av[q] * hv[q].w;
      }
    }
#pragma unroll
    for (int o = 16; o < 64; o <<= 1) {
      acc.x += __shfl_xor(acc.x, o);
      acc.y += __shfl_xor(acc.y, o);
      acc.z += __shfl_xor(acc.z, o);
      acc.w += __shfl_xor(acc.w, o);
    }
  }
  if (g == 0)
    *(float4*)&out[(size_t)node * OUT_C + c * 4] = acc;
}

// ---------------- launch ----------------
extern "C" void kernel_launch(void* const* d_in, const int* in_sizes, int n_in,
                              void* d_out, int out_size, void* d_ws, size_t ws_size,
                              hipStream_t stream) {
  const float* x   = (const float*)d_in[0];
  const float* w   = (const float*)d_in[1];
  const float* att = (const float*)d_in[2];
  const int*   ei  = (const int*)d_in[3];

  int N = in_sizes[0] / IN_C;
  int E = in_sizes[3] / 2;
  int EN = E + N;
  const int* src = ei;
  const int* tgt = ei + E;

  float* out      = (float*)d_out;
  float* out_edge = out + (size_t)N * OUT_C;
  float* out_node = out_edge + (size_t)EN;

  char* p = (char*)d_ws;
  auto alloc = [&](size_t bytes) -> char* {
    char* r = p;
    p += (bytes + 255) & ~(size_t)255;
    return r;
  };
  float* h     = (float*)alloc((size_t)N * OUT_C * 4);
  float* ai    = (float*)alloc((size_t)N * 4);
  float* aj    = (float*)alloc((size_t)N * 4);
  u32*   bufA  = (u32*)alloc((size_t)EN * 4);      // CSR items ((tgt&255)<<24 | src)
  u64*   bufB  = (u64*)alloc((size_t)EN * 8);      // staging / src-pairs / agg-pairs
  float* alpha = (float*)alloc((size_t)EN * 4);    // alpha in CSR order
  u32*   offT  = (u32*)alloc((size_t)(N + 1) * 4);
  u32*   gh    = (u32*)alloc((size_t)NGH * 4);     // tgt hist: d*RB + rawblock
  u32*   ghs   = (u32*)alloc((size_t)NGHS * 4);    // src hist: sbin*RBINS + tgtbucket
  u32*   bsum  = (u32*)alloc(2048 * 4);
  float* asum  = (float*)alloc((size_t)N * 4);
  u32*   nm    = (u32*)alloc((size_t)N * 4);
  u32*   hist8 = (u32*)alloc(2048 * 4);
  u32*   done  = (u32*)alloc(8 * 4);
  u32*   cnt   = (u32*)alloc(8 * 4);
  u32*   sel   = (u32*)alloc(256);
  u32*   listA = (u32*)alloc((size_t)N * 4);
  u32*   listB = (u32*)alloc((size_t)N * 4);

  u32 kSel = (u32)((N + 1) / 2);
  int chunk = (EN + RB - 1) / RB;
  int nScanT = (NGH + 255) / 256;    // 512
  int nScanS = (NGHS + 255) / 256;   // 1024
  int gRow = (N + 255) / 256;
  int gN = (N + 255) / 256;
  int gE = (EN + 255) / 256;
  int gNode4 = (N + 3) / 4;
  int gNode16 = (N + 15) / 16;

  k_init<<<8, 256, 0, stream>>>(hist8, done, sel, cnt, kSel);
  k_gemm<<<gRow, 256, 0, stream>>>(x, w, att, h, ai, aj, N);

  // ---- partition by target (coarse raw-order + fine per-bucket) -> bufA = CSR, offT ----
  k_rhist_t<<<RB, 256, 0, stream>>>(tgt, E, EN, chunk, gh);
  k_scanA<<<nScanT, 256, 0, stream>>>(gh, gh, bsum, NGH);
  k_scanB<<<1, 1024, 0, stream>>>(bsum, nScanT);
  k_scanC<<<nScanT, 256, 0, stream>>>(gh, bsum, NGH);
  k_rscatter_t<<<RB, 256, 0, stream>>>(src, tgt, E, EN, chunk, gh, (u32*)bufB);
  k_rpass2<<<RBINS, 256, 0, stream>>>((u32*)bufB, bufA, gh, ghs, offT, N, EN);

  k_softmax<<<gNode16, 256, 0, stream>>>(bufA, offT, ai, aj, alpha, N);

  // ---- src partition: hist came fused from k_rpass2 (same iteration space as scatter) ----
  k_scanA<<<nScanS, 256, 0, stream>>>(ghs, ghs, bsum, NGHS);
  k_scanB<<<1, 1024, 0, stream>>>(bsum, nScanS);
  k_scanC<<<nScanS, 256, 0, stream>>>(ghs, bsum, NGHS);
  k_rscatter_s<<<RBINS, 256, 0, stream>>>(bufA, alpha, gh, ghs, bufB, EN);
  k_asum_acc<<<RBINS, 256, 0, stream>>>(bufB, ghs, asum, N, EN);

  // ---- exact top-k: 4 radix passes (fenc) + 1 tie-break finish ----
  k_histpick<<<gN, 256, 0, stream>>>(asum, nullptr, nullptr, nullptr, nullptr,
                                     hist8, done, sel, N, 0, gN);
  k_histpick<<<gN, 256, 0, stream>>>(asum, nullptr, nullptr, listA, &cnt[1],
                                     hist8, done, sel, N, 1, gN);
  k_histpick<<<gN, 256, 0, stream>>>(asum, listA, &cnt[1], listB, &cnt[2],
                                     hist8, done, sel, N, 2, gN);
  k_histpick<<<gN, 256, 0, stream>>>(asum, listB, &cnt[2], listA, &cnt[3],
                                     hist8, done, sel, N, 3, gN);
  k_finish<<<1, 256, 0, stream>>>(asum, listA, &cnt[3], sel);

  k_node_mask<<<gN, 256, 0, stream>>>(asum, sel, nm, out_node, N);
  k_mask<<<gE, 256, 0, stream>>>(src, tgt, nm, bufA, alpha, out_edge, bufB, E, EN);
  k_aggregate<<<gNode4, 256, 0, stream>>>(offT, bufB, h, nm, out, N);
}

// Round 7
// 372.879 us; speedup vs baseline: 1.5634x; 1.0086x over previous
//
#include <hip/hip_runtime.h>
#include <stdint.h>

#define IN_C 128
#define OUT_C 64
#define NEG_SLOPE 0.2f
#define RB 256      // blocks in coarse-partition kernels
#define RBINS 512   // coarse bins (node>>8, node<131072)
#define STAGE 8192  // per-bucket LDS staging capacity (max bucket ~4.7k)
#define NGH (RBINS * RB)       // 131072 (tgt histogram)
#define NGHS (RBINS * RBINS)   // 262144 (src histogram: sbin*512 + tgt-bucket)
#define KC 8                   // gemm k-chunk
#define SXW 384                // sx words per kl: 32 rowgroups * 12 (8 rows + 4 pad)

typedef unsigned int u32;
typedef unsigned long long u64;

// ---------------- helpers ----------------
__device__ __forceinline__ u32 fenc(float f) {
  u32 u = __float_as_uint(f);
  return (u & 0x80000000u) ? ~u : (u | 0x80000000u);
}
__device__ __forceinline__ u64 key64(float v, int i) {
  return (((u64)fenc(v)) << 32) | (u64)(0xffffffffu - (u32)i);
}

// ---------------- h = x @ W + fused ai/aj epilogue ----------------
// 256-row tile, 8x8/thread. K in 16 chunks of 8. LDS 44.4 KB -> 3 blocks/CU.
// sx row layout phys(row)=(row>>3)*12+(row&7): b128 read quads = 3*rg mod 8 (all distinct).
__global__ __launch_bounds__(256) void k_gemm(const float* __restrict__ x,
                                              const float* __restrict__ w,
                                              const float* __restrict__ att,
                                              float* __restrict__ h,
                                              float* __restrict__ ai, float* __restrict__ aj,
                                              int N) {
  __shared__ float sw[IN_C * OUT_C];   // 32 KB
  __shared__ float sx[KC * SXW];       // 12 KB
  int tid = threadIdx.x;
  int rbase = blockIdx.x * 256;

  for (int i = tid; i < (IN_C * OUT_C) / 4; i += 256)
    ((float4*)sw)[i] = ((const float4*)w)[i];

  int c0 = (tid & 7) * 8;        // 8 col groups
  int rg = tid >> 3;             // 32 row groups x 8 rows
  int sxbase = rg * 12;
  float acc[8][8];
#pragma unroll
  for (int i = 0; i < 8; i++)
#pragma unroll
    for (int j = 0; j < 8; j++) acc[i][j] = 0.f;

  // staging assignment: it in {0,1}: row=(tid>>1)+it*128, kq4=tid&1
  int str = tid >> 1;
  int skq = tid & 1;

  for (int kb = 0; kb < IN_C; kb += KC) {
    __syncthreads();
#pragma unroll
    for (int it = 0; it < 2; ++it) {
      int r = str + it * 128;
      int grow = rbase + r;
      float4 v = make_float4(0.f, 0.f, 0.f, 0.f);
      if (grow < N) v = *(const float4*)&x[(size_t)grow * IN_C + kb + skq * 4];
      int base = (r >> 3) * 12 + (r & 7);
      sx[(skq * 4 + 0) * SXW + base] = v.x;
      sx[(skq * 4 + 1) * SXW + base] = v.y;
      sx[(skq * 4 + 2) * SXW + base] = v.z;
      sx[(skq * 4 + 3) * SXW + base] = v.w;
    }
    __syncthreads();
#pragma unroll
    for (int kl = 0; kl < KC; ++kl) {
      int kg = kb + kl;
      float xr[8], wv[8];
      *(float4*)&xr[0] = *(const float4*)&sx[kl * SXW + sxbase];
      *(float4*)&xr[4] = *(const float4*)&sx[kl * SXW + sxbase + 4];
      *(float4*)&wv[0] = *(const float4*)&sw[kg * OUT_C + c0];
      *(float4*)&wv[4] = *(const float4*)&sw[kg * OUT_C + c0 + 4];
#pragma unroll
      for (int i = 0; i < 8; ++i)
#pragma unroll
        for (int j = 0; j < 8; ++j)
          acc[i][j] += xr[i] * wv[j];
    }
  }

  float pi[8], pj[8];
#pragma unroll
  for (int i = 0; i < 8; ++i) { pi[i] = 0.f; pj[i] = 0.f; }
#pragma unroll
  for (int j = 0; j < 8; ++j) {
    float a0 = att[c0 + j], a1 = att[OUT_C + c0 + j];
#pragma unroll
    for (int i = 0; i < 8; ++i) {
      pi[i] += acc[i][j] * a0;
      pj[i] += acc[i][j] * a1;
    }
  }
#pragma unroll
  for (int o = 1; o < 8; o <<= 1) {
#pragma unroll
    for (int i = 0; i < 8; ++i) {
      pi[i] += __shfl_xor(pi[i], o);
      pj[i] += __shfl_xor(pj[i], o);
    }
  }
#pragma unroll
  for (int i = 0; i < 8; ++i) {
    int row = rbase + rg * 8 + i;
    if (row < N) {
      *(float4*)&h[(size_t)row * OUT_C + c0]     = make_float4(acc[i][0], acc[i][1], acc[i][2], acc[i][3]);
      *(float4*)&h[(size_t)row * OUT_C + c0 + 4] = make_float4(acc[i][4], acc[i][5], acc[i][6], acc[i][7]);
      if ((tid & 7) == 0) { ai[row] = pi[i]; aj[row] = pj[i]; }
    }
  }
}

// ---------------- coarse hist by tgt>>8 + fused select-state init ----------------
__global__ __launch_bounds__(256) void k_rhist_t(const int* __restrict__ tgt,
                                                 int E, int EN, int chunk, u32* __restrict__ gh,
                                                 u32* __restrict__ hist8, u32* __restrict__ done,
                                                 u32* __restrict__ sel, u32* __restrict__ cnt, u32 k) {
  __shared__ u32 lh[RBINS];
  int tid = threadIdx.x, b = blockIdx.x;
  if (b == 0) {   // fused init (serialized before any consumer kernel)
    for (int i = tid; i < 2048; i += 256) hist8[i] = 0u;
    if (tid < 8) { done[tid] = 0u; cnt[tid] = 0u; }
    if (tid == 0) { sel[0] = 0u; sel[1] = 0u; sel[2] = k; sel[3] = 0u; }
  }
  for (int d = tid; d < RBINS; d += 256) lh[d] = 0u;
  __syncthreads();
  int lo = b * chunk, hi = min(lo + chunk, EN);
  for (int e = lo + tid; e < hi; e += 256) {
    int t = (e < E) ? tgt[e] : e - E;
    atomicAdd(&lh[((u32)t) >> 8], 1u);
  }
  __syncthreads();
  for (int d = tid; d < RBINS; d += 256) gh[d * RB + b] = lh[d];
}

// ---------------- generic 3-kernel exclusive scan (n <= 262144) ----------------
__global__ __launch_bounds__(256) void k_scanA(const u32* __restrict__ in, u32* __restrict__ out,
                                               u32* __restrict__ bsum, int n) {
  __shared__ u32 s[256];
  int i = blockIdx.x * 256 + threadIdx.x;
  u32 v = (i < n) ? in[i] : 0u;
  s[threadIdx.x] = v;
  __syncthreads();
  for (int o = 1; o < 256; o <<= 1) {
    u32 t = (threadIdx.x >= (unsigned)o) ? s[threadIdx.x - o] : 0u;
    __syncthreads();
    s[threadIdx.x] += t;
    __syncthreads();
  }
  if (i < n) out[i] = s[threadIdx.x] - v;
  if (threadIdx.x == 255) bsum[blockIdx.x] = s[255];
}

__global__ __launch_bounds__(1024) void k_scanB(u32* __restrict__ bsum, int nb) {
  __shared__ u32 s[1024];
  int tid = threadIdx.x;
  u32 v = (tid < nb) ? bsum[tid] : 0u;
  s[tid] = v;
  __syncthreads();
  for (int o = 1; o < 1024; o <<= 1) {
    u32 t = (tid >= o) ? s[tid - o] : 0u;
    __syncthreads();
    s[tid] += t;
    __syncthreads();
  }
  if (tid < nb) bsum[tid] = s[tid] - v;
}

__global__ __launch_bounds__(256) void k_scanC(u32* __restrict__ out, const u32* __restrict__ bsum, int n) {
  int i = blockIdx.x * 256 + threadIdx.x;
  if (i < n) out[i] += bsum[blockIdx.x];
}

// ---------------- coarse scatter by tgt>>8: u32 items ((tgt&255)<<24 | src) ----------------
__global__ __launch_bounds__(256) void k_rscatter_t(const int* __restrict__ src, const int* __restrict__ tgt,
                                                    int E, int EN, int chunk,
                                                    const u32* __restrict__ gh, u32* __restrict__ bufB) {
  __shared__ u32 cnt[RBINS];
  int tid = threadIdx.x, b = blockIdx.x;
  for (int d = tid; d < RBINS; d += 256) cnt[d] = gh[d * RB + b];
  __syncthreads();
  int lo = b * chunk, hi = min(lo + chunk, EN);
  for (int e = lo + tid; e < hi; e += 256) {
    int s, t;
    if (e < E) { s = src[e]; t = tgt[e]; } else { s = t = e - E; }
    u32 p = atomicAdd(&cnt[((u32)t) >> 8], 1u);
    bufB[p] = (((u32)t & 255u) << 24) | (u32)s;
  }
}

// ---------------- fine partition + CSR offsets + fused src>>8 hist + FUSED SOFTMAX ----
__global__ __launch_bounds__(256) void k_rpass2(const u32* __restrict__ in, u32* __restrict__ out,
                                                const u32* __restrict__ gh, u32* __restrict__ ghs,
                                                u32* __restrict__ offT,
                                                const float* __restrict__ ai, const float* __restrict__ aj,
                                                float* __restrict__ alpha,
                                                int N, int EN) {
  __shared__ u32 hist[256];
  __shared__ u32 sc[256];
  __shared__ u32 lhs[RBINS];
  __shared__ u32 stage[STAGE];
  int tid = threadIdx.x, d = blockIdx.x;
  u32 start = gh[d * RB];
  u32 end = (d < RBINS - 1) ? gh[(d + 1) * RB] : (u32)EN;
  int sz = (int)(end - start);
  hist[tid] = 0u;
  for (int dd = tid; dd < RBINS; dd += 256) lhs[dd] = 0u;
  __syncthreads();
  for (u32 p = start + tid; p < end; p += 256) {
    u32 it = in[p];
    atomicAdd(&hist[it >> 24], 1u);
    atomicAdd(&lhs[(it & 0xffffffu) >> 8], 1u);
  }
  __syncthreads();
  for (int dd = tid; dd < RBINS; dd += 256) ghs[dd * RBINS + d] = lhs[dd];
  u32 hv = hist[tid];
  sc[tid] = hv;
  __syncthreads();
  for (int o = 1; o < 256; o <<= 1) {
    u32 t = (tid >= o) ? sc[tid - o] : 0u;
    __syncthreads();
    sc[tid] += t;
    __syncthreads();
  }
  u32 excl = sc[tid] - hv;
  int node = (d << 8) + tid;
  if (node < N) offT[node] = start + excl;
  if (node == 0) offT[N] = (u32)EN;
  hist[tid] = excl;   // running cursor
  __syncthreads();
  bool staged = (sz <= STAGE);
  for (u32 p = start + tid; p < end; p += 256) {
    u32 it = in[p];
    u32 lp = atomicAdd(&hist[it >> 24], 1u);
    if (staged) stage[lp] = it;
    else out[start + lp] = it;
  }
  __syncthreads();
  if (staged)
    for (int i = tid; i < sz; i += 256) out[start + i] = stage[i];
  __syncthreads();
  // ---- fused per-node softmax: thread = node, edges in stage (or out if !staged) ----
  if (node < N) {
    int lb = (tid > 0) ? (int)sc[tid - 1] : 0;
    int le = (int)sc[tid];
    float an = ai[node];
    float mx = -1e30f;
    for (int i = lb; i < le; ++i) {
      u32 it = staged ? stage[i] : out[start + i];
      float a = an + aj[it & 0xffffffu];
      a = a > 0.f ? a : NEG_SLOPE * a;
      mx = fmaxf(mx, a);
      if (staged) stage[i] = __float_as_uint(a);   // cache raw a (src no longer needed in LDS)
    }
    float sm = 0.f;
    for (int i = lb; i < le; ++i) {
      float a;
      if (staged) a = __uint_as_float(stage[i]);
      else {
        u32 it = out[start + i];
        a = an + aj[it & 0xffffffu];
        a = a > 0.f ? a : NEG_SLOPE * a;
      }
      float v = expf(a - mx);
      sm += v;
      if (staged) stage[i] = __float_as_uint(v);
      else alpha[start + i] = v;
    }
    float inv = 1.f / (sm + 1e-16f);
    for (int i = lb; i < le; ++i) {
      float v = staged ? __uint_as_float(stage[i]) : alpha[start + i];
      alpha[start + i] = v * inv;
    }
  }
}

// ---------------- scatter by src>>8 over the SAME per-bucket ranges as k_rpass2 ----------------
__global__ __launch_bounds__(256) void k_rscatter_s(const u32* __restrict__ csr,
                                                    const float* __restrict__ alpha,
                                                    const u32* __restrict__ gh, const u32* __restrict__ ghs,
                                                    u64* __restrict__ bufB, int EN) {
  __shared__ u32 cnt[RBINS];
  int tid = threadIdx.x, d = blockIdx.x;
  for (int dd = tid; dd < RBINS; dd += 256) cnt[dd] = ghs[dd * RBINS + d];
  __syncthreads();
  u32 start = gh[d * RB];
  u32 end = (d < RBINS - 1) ? gh[(d + 1) * RB] : (u32)EN;
  for (u32 e = start + tid; e < end; e += 256) {
    u32 s = csr[e] & 0xffffffu;
    u32 p = atomicAdd(&cnt[s >> 8], 1u);
    bufB[p] = (((u64)(s & 255u)) << 32) | __float_as_uint(alpha[e]);
  }
}

// ---------------- per-bucket alpha_sum accumulation (LDS fp bins) ----------------
__global__ __launch_bounds__(256) void k_asum_acc(const u64* __restrict__ bufB,
                                                  const u32* __restrict__ ghs,
                                                  float* __restrict__ asum, int N, int EN) {
  __shared__ float sums[256];
  int tid = threadIdx.x, d = blockIdx.x;
  u32 start = ghs[d * RBINS];
  u32 end = (d < RBINS - 1) ? ghs[(d + 1) * RBINS] : (u32)EN;
  sums[tid] = 0.f;
  __syncthreads();
  for (u32 p = start + tid; p < end; p += 256) {
    u64 it = bufB[p];
    atomicAdd(&sums[(u32)(it >> 32)], __uint_as_float((u32)it));
  }
  __syncthreads();
  int node = d * 256 + tid;
  if (node < N) asum[node] = sums[tid];
}

// ---------------- fused radix-select pass: hist + append + last-block pick ----------------
__global__ __launch_bounds__(256) void k_histpick(const float* __restrict__ asum,
                                                  const u32* __restrict__ list_in, const u32* __restrict__ cnt_in,
                                                  u32* __restrict__ list_out, u32* __restrict__ cnt_out,
                                                  u32* __restrict__ hist8, u32* __restrict__ done,
                                                  u32* __restrict__ sel, int N, int pass, int nblk) {
  __shared__ u32 lh[256];
  __shared__ u32 sres;
  __shared__ u32 s[256];
  int tid = threadIdx.x;
  lh[tid] = 0u;
  __syncthreads();
  u64 prefix = ((const u64*)sel)[0];
  int shift = 56 - 8 * pass;
  int n = list_in ? (int)*cnt_in : N;
  int i = blockIdx.x * 256 + tid;
  if (i < n) {
    int idx = list_in ? (int)list_in[i] : i;
    u64 k = key64(asum[idx], idx);
    bool ok = (pass == 0) || ((k >> (shift + 8)) == prefix);
    if (ok) {
      atomicAdd(&lh[(u32)(k >> shift) & 255u], 1u);
      if (list_out) {
        u32 p = atomicAdd(cnt_out, 1u);
        list_out[p] = (u32)idx;
      }
    }
  }
  __syncthreads();
  if (lh[tid]) atomicAdd(&hist8[pass * 256 + tid], lh[tid]);
  __syncthreads();
  if (tid == 0)
    sres = __hip_atomic_fetch_add(&done[pass], 1u, __ATOMIC_ACQ_REL, __HIP_MEMORY_SCOPE_AGENT);
  __syncthreads();
  if (sres == (u32)(nblk - 1)) {
    u32 krem = sel[2];
    u32 hv = __hip_atomic_load(&hist8[pass * 256 + (255 - tid)], __ATOMIC_RELAXED,
                               __HIP_MEMORY_SCOPE_AGENT);
    s[tid] = hv;
    __syncthreads();
    for (int o = 1; o < 256; o <<= 1) {
      u32 t = (tid >= o) ? s[tid - o] : 0u;
      __syncthreads();
      s[tid] += t;
      __syncthreads();
    }
    u32 cum = s[tid], prev = (tid > 0) ? s[tid - 1] : 0u;
    if (cum >= krem && prev < krem) {
      int dsel = 255 - tid;
      ((u64*)sel)[0] = (prefix << 8) | (u64)(u32)dsel;
      sel[2] = krem - prev;
    }
  }
}

// ---------------- finish select: fenc fixed after 4 passes; rank-select index ties ----------------
__global__ __launch_bounds__(256) void k_finish(const float* __restrict__ asum,
                                                const u32* __restrict__ list, const u32* __restrict__ cntp,
                                                u32* __restrict__ sel) {
  __shared__ u64 keys[2048];
  __shared__ u32 cc;
  int tid = threadIdx.x;
  if (tid == 0) cc = 0u;
  __syncthreads();
  int n = (int)*cntp;
  u32 fsel = (u32)((const u64*)sel)[0];
  u32 krem = sel[2];
  for (int i = tid; i < n; i += 256) {
    int idx = (int)list[i];
    u64 k = key64(asum[idx], idx);
    if ((u32)(k >> 32) == fsel) {
      u32 p = atomicAdd(&cc, 1u);
      if (p < 2048) keys[p] = k;
    }
  }
  __syncthreads();
  int C = (int)min(cc, 2048u);
  for (int i = tid; i < C; i += 256) {
    u64 k = keys[i];
    u32 rank = 0;
    for (int j = 0; j < C; ++j)
      if (keys[j] > k) rank++;
    if (rank == krem - 1) ((u64*)sel)[0] = k;
  }
}

// ---------------- node mask ----------------
__global__ __launch_bounds__(256) void k_node_mask(const float* __restrict__ asum,
                                                   const u32* __restrict__ sel,
                                                   u32* __restrict__ nm,
                                                   float* __restrict__ out_node, int N) {
  int i = blockIdx.x * 256 + threadIdx.x;
  if (i >= N) return;
  u64 T = ((const u64*)sel)[0];
  bool m = key64(asum[i], i) >= T;
  nm[i] = m ? 1u : 0u;
  out_node[i] = m ? 1.f : 0.f;
}

// ---------------- fused: raw-order edge mask + CSR-order premasked (src,alpha) pairs ----------------
__global__ __launch_bounds__(256) void k_mask(const int* __restrict__ src, const int* __restrict__ tgt,
                                              const u32* __restrict__ nm,
                                              const u32* __restrict__ csr, const float* __restrict__ alpha,
                                              float* __restrict__ out_edge, u64* __restrict__ pair,
                                              int E, int EN) {
  int e = blockIdx.x * 256 + threadIdx.x;
  if (e >= EN) return;
  int s, t;
  if (e < E) { s = src[e]; t = tgt[e]; } else { s = t = e - E; }
  out_edge[e] = (nm[s] && nm[t]) ? 1.f : 0.f;
  u32 sp = csr[e] & 0xffffffu;
  u32 ab = nm[sp] ? __float_as_uint(alpha[e]) : 0u;
  pair[e] = (((u64)sp) << 32) | ab;
}

// ---------------- aggregate: branchless, 4-slot software pipeline per group ----------------
__global__ __launch_bounds__(256) void k_aggregate(const u32* __restrict__ off,
                                                   const u64* __restrict__ pair,
                                                   const float* __restrict__ h,
                                                   const u32* __restrict__ nm,
                                                   float* __restrict__ out, int N) {
  int node = blockIdx.x * 4 + (threadIdx.x >> 6);
  int lane = threadIdx.x & 63;
  int g = lane >> 4;
  int c = lane & 15;
  if (node >= N) return;
  float4 acc = make_float4(0.f, 0.f, 0.f, 0.f);
  if (nm[node]) {
    u32 b = off[node], e2 = off[node + 1];
    for (u32 p0 = b; p0 < e2; p0 += 16) {
      u64 pr[4];
      float av[4];
      u32 sv[4];
#pragma unroll
      for (int q = 0; q < 4; ++q) {
        u32 p = p0 + q * 4 + (u32)g;
        bool ok = p < e2;
        pr[q] = pair[ok ? p : b];
        av[q] = ok ? __uint_as_float((u32)pr[q]) : 0.f;
        sv[q] = (u32)(pr[q] >> 32);
      }
      float4 hv[4];
#pragma unroll
      for (int q = 0; q < 4; ++q)
        hv[q] = *(const float4*)&h[(size_t)sv[q] * OUT_C + c * 4];
#pragma unroll
      for (int q = 0; q < 4; ++q) {
        acc.x += av[q] * hv[q].x;
        acc.y += av[q] * hv[q].y;
        acc.z += av[q] * hv[q].z;
        acc.w += av[q] * hv[q].w;
      }
    }
#pragma unroll
    for (int o = 16; o < 64; o <<= 1) {
      acc.x += __shfl_xor(acc.x, o);
      acc.y += __shfl_xor(acc.y, o);
      acc.z += __shfl_xor(acc.z, o);
      acc.w += __shfl_xor(acc.w, o);
    }
  }
  if (g == 0)
    *(float4*)&out[(size_t)node * OUT_C + c * 4] = acc;
}

// ---------------- launch ----------------
extern "C" void kernel_launch(void* const* d_in, const int* in_sizes, int n_in,
                              void* d_out, int out_size, void* d_ws, size_t ws_size,
                              hipStream_t stream) {
  const float* x   = (const float*)d_in[0];
  const float* w   = (const float*)d_in[1];
  const float* att = (const float*)d_in[2];
  const int*   ei  = (const int*)d_in[3];

  int N = in_sizes[0] / IN_C;
  int E = in_sizes[3] / 2;
  int EN = E + N;
  const int* src = ei;
  const int* tgt = ei + E;

  float* out      = (float*)d_out;
  float* out_edge = out + (size_t)N * OUT_C;
  float* out_node = out_edge + (size_t)EN;

  char* p = (char*)d_ws;
  auto alloc = [&](size_t bytes) -> char* {
    char* r = p;
    p += (bytes + 255) & ~(size_t)255;
    return r;
  };
  float* h     = (float*)alloc((size_t)N * OUT_C * 4);
  float* ai    = (float*)alloc((size_t)N * 4);
  float* aj    = (float*)alloc((size_t)N * 4);
  u32*   bufA  = (u32*)alloc((size_t)EN * 4);      // CSR items ((tgt&255)<<24 | src)
  u64*   bufB  = (u64*)alloc((size_t)EN * 8);      // staging / src-pairs / agg-pairs
  float* alpha = (float*)alloc((size_t)EN * 4);    // alpha in CSR order
  u32*   offT  = (u32*)alloc((size_t)(N + 1) * 4);
  u32*   gh    = (u32*)alloc((size_t)NGH * 4);     // tgt hist: d*RB + rawblock
  u32*   ghs   = (u32*)alloc((size_t)NGHS * 4);    // src hist: sbin*RBINS + tgtbucket
  u32*   bsum  = (u32*)alloc(2048 * 4);
  float* asum  = (float*)alloc((size_t)N * 4);
  u32*   nm    = (u32*)alloc((size_t)N * 4);
  u32*   hist8 = (u32*)alloc(2048 * 4);
  u32*   done  = (u32*)alloc(8 * 4);
  u32*   cnt   = (u32*)alloc(8 * 4);
  u32*   sel   = (u32*)alloc(256);
  u32*   listA = (u32*)alloc((size_t)N * 4);
  u32*   listB = (u32*)alloc((size_t)N * 4);

  u32 kSel = (u32)((N + 1) / 2);
  int chunk = (EN + RB - 1) / RB;
  int nScanT = (NGH + 255) / 256;    // 512
  int nScanS = (NGHS + 255) / 256;   // 1024
  int gRow = (N + 255) / 256;
  int gN = (N + 255) / 256;
  int gE = (EN + 255) / 256;
  int gNode4 = (N + 3) / 4;

  k_gemm<<<gRow, 256, 0, stream>>>(x, w, att, h, ai, aj, N);

  // ---- partition by target (coarse raw-order + fine per-bucket) -> bufA = CSR, offT ----
  k_rhist_t<<<RB, 256, 0, stream>>>(tgt, E, EN, chunk, gh, hist8, done, sel, cnt, kSel);
  k_scanA<<<nScanT, 256, 0, stream>>>(gh, gh, bsum, NGH);
  k_scanB<<<1, 1024, 0, stream>>>(bsum, nScanT);
  k_scanC<<<nScanT, 256, 0, stream>>>(gh, bsum, NGH);
  k_rscatter_t<<<RB, 256, 0, stream>>>(src, tgt, E, EN, chunk, gh, (u32*)bufB);
  k_rpass2<<<RBINS, 256, 0, stream>>>((u32*)bufB, bufA, gh, ghs, offT, ai, aj, alpha, N, EN);

  // ---- src partition: hist came fused from k_rpass2 (same iteration space as scatter) ----
  k_scanA<<<nScanS, 256, 0, stream>>>(ghs, ghs, bsum, NGHS);
  k_scanB<<<1, 1024, 0, stream>>>(bsum, nScanS);
  k_scanC<<<nScanS, 256, 0, stream>>>(ghs, bsum, NGHS);
  k_rscatter_s<<<RBINS, 256, 0, stream>>>(bufA, alpha, gh, ghs, bufB, EN);
  k_asum_acc<<<RBINS, 256, 0, stream>>>(bufB, ghs, asum, N, EN);

  // ---- exact top-k: 4 radix passes (fenc) + 1 tie-break finish ----
  k_histpick<<<gN, 256, 0, stream>>>(asum, nullptr, nullptr, nullptr, nullptr,
                                     hist8, done, sel, N, 0, gN);
  k_histpick<<<gN, 256, 0, stream>>>(asum, nullptr, nullptr, listA, &cnt[1],
                                     hist8, done, sel, N, 1, gN);
  k_histpick<<<gN, 256, 0, stream>>>(asum, listA, &cnt[1], listB, &cnt[2],
                                     hist8, done, sel, N, 2, gN);
  k_histpick<<<gN, 256, 0, stream>>>(asum, listB, &cnt[2], listA, &cnt[3],
                                     hist8, done, sel, N, 3, gN);
  k_finish<<<1, 256, 0, stream>>>(asum, listA, &cnt[3], sel);

  k_node_mask<<<gN, 256, 0, stream>>>(asum, sel, nm, out_node, N);
  k_mask<<<gE, 256, 0, stream>>>(src, tgt, nm, bufA, alpha, out_edge, bufB, E, EN);
  k_aggregate<<<gNode4, 256, 0, stream>>>(offT, bufB, h, nm, out, N);
}